// Round 12
// baseline (1088.505 us; speedup 1.0000x reference)
//
#include <hip/hip_runtime.h>
#include <hip/hip_bf16.h>
#include <stdint.h>

#define NN 100000   // nodes
#define DD 128      // input dim
#define OO 128      // output dim
#define NS 8        // relations
#define NB 4        // bases

#define BROWS 128   // rows per bucket
#define NBUCK 782   // ceil(NN/BROWS)
#define SDEPTH 16   // bin LDS staging depth per bucket (flush = 16 entries = 128B line)
#define BCAP 4608   // per-bucket capacity for a 2-relation group (mean 4092 + 8 sigma)
#define CPAD 16     // cursor padding (ints) = 64B per counter

typedef __attribute__((ext_vector_type(8))) short short8;
typedef __attribute__((ext_vector_type(4))) float f32x4;

__device__ __forceinline__ float bf2f(uint16_t u){
  union { uint32_t i; float f; } x; x.i = ((uint32_t)u) << 16; return x.f;
}
__device__ __forceinline__ uint16_t f2bf(float f){
  union { float f; uint32_t i; } x; x.f = f;
  uint32_t r = (x.i + 0x7FFFu + ((x.i >> 16) & 1u)) >> 16;  // RNE
  return (uint16_t)r;
}

// ---- effective per-relation weight, TRANSPOSED: Vt[s][o][d] = M_s[d][o] ----
// M_s[d,o] = sum_b W_comp[d&7, b] * W[b*128 + s*16 + (d>>3), o]  (validated R1-R11)
__global__ void vt_kernel(const float* __restrict__ W, const float* __restrict__ Wc,
                          uint16_t* __restrict__ Vt){
  int d  = threadIdx.x;
  int so = blockIdx.x;
  int s = so >> 7, o = so & 127;
  int wrow = s * 16 + (d >> 3);
  int wci  = (d & 7) * NB;
  float acc = 0.f;
#pragma unroll
  for (int b = 0; b < NB; ++b)
    acc += Wc[wci + b] * W[(b * DD + wrow) * OO + o];
  Vt[so * DD + d] = f2bf(acc);
}

// ---- gemm2: H_{s0}, H_{s0+1} = X @ M; reads f32 X once, casts in-register (R10-validated) ----
__global__ __launch_bounds__(256) void gemm2_kernel(const float* __restrict__ X,
                                                    const uint16_t* __restrict__ Vt2,
                                                    uint16_t* __restrict__ H2){
  const int wave = threadIdx.x >> 6;
  const int lane = threadIdx.x & 63;
  const int lr = lane & 15, lk = lane >> 4;
  const int row0 = blockIdx.x * 64 + wave * 16;

  int arow = row0 + lr; if (arow >= NN) arow = NN - 1;
  const float* ap = X + (size_t)arow * DD;
  short8 a[4];
#pragma unroll
  for (int kb = 0; kb < 4; ++kb){
    float4 f0 = *(const float4*)(ap + kb * 32 + lk * 8);
    float4 f1 = *(const float4*)(ap + kb * 32 + lk * 8 + 4);
    short8 t;
    t[0] = (short)f2bf(f0.x); t[1] = (short)f2bf(f0.y);
    t[2] = (short)f2bf(f0.z); t[3] = (short)f2bf(f0.w);
    t[4] = (short)f2bf(f1.x); t[5] = (short)f2bf(f1.y);
    t[6] = (short)f2bf(f1.z); t[7] = (short)f2bf(f1.w);
    a[kb] = t;
  }

  for (int j = 0; j < 2; ++j){
    f32x4 acc[8];
#pragma unroll
    for (int t = 0; t < 8; ++t) acc[t] = (f32x4){0.f, 0.f, 0.f, 0.f};
    const uint16_t* vb = Vt2 + (size_t)j * OO * DD;
#pragma unroll
    for (int kb = 0; kb < 4; ++kb){
#pragma unroll
      for (int t = 0; t < 8; ++t){
        short8 b = *(const short8*)(vb + (size_t)(t * 16 + lr) * DD + kb * 32 + lk * 8);
        acc[t] = __builtin_amdgcn_mfma_f32_16x16x32_bf16(a[kb], b, acc[t], 0, 0, 0);
      }
    }
    uint16_t* hs = H2 + (size_t)j * NN * OO;
#pragma unroll
    for (int t = 0; t < 8; ++t){
#pragma unroll
      for (int jj = 0; jj < 4; ++jj){
        int r = row0 + lk * 4 + jj;
        if (r < NN) hs[(size_t)r * OO + t * 16 + lr] = f2bf(acc[t][jj]);
      }
    }
  }
}

// overflow entry decode: rl[0:6], col[7:23], s[24]
__device__ __noinline__ void overflow_add(int r, int c, int srel, float v,
                                          const uint16_t* __restrict__ H2,
                                          float* __restrict__ out){
  const uint16_t* h = H2 + (size_t)srel * NN * OO + (size_t)c * OO;
  float* dst = out + (size_t)r * OO;
  for (int d = 0; d < OO; ++d) unsafeAtomicAdd(dst + d, v * bf2f(h[d]));
}

// ---- bin3: multisplit 2 relations' edges into row-buckets; 2 edges/thread/round (R11-validated) ----
__global__ __launch_bounds__(1024) void bin3_kernel(const int* __restrict__ rows2,
                                                    const int* __restrict__ cols2,
                                                    const float* __restrict__ vals2,
                                                    const uint16_t* __restrict__ H2,
                                                    int* __restrict__ cursor,
                                                    uint2* __restrict__ gbuf,
                                                    float* __restrict__ out,
                                                    int E, int chunk, int rounds){
  __shared__ uint2 stage[NBUCK][SDEPTH];   // 100,096 B
  __shared__ int   scnt[NBUCK];            //   3,128 B
  const int tid = threadIdx.x;
  const int E2 = 2 * E;
  for (int i = tid; i < NBUCK; i += 1024) scnt[i] = 0;
  __syncthreads();
  const int e0 = blockIdx.x * chunk;
  for (int rd = 0; rd < rounds; ++rd){
    int r2[2], c2[2]; float v2[2]; uint32_t sr2[2]; bool ok[2];
#pragma unroll
    for (int k = 0; k < 2; ++k){
      int idx = rd * 2048 + k * 1024 + tid;
      int e = e0 + idx;
      ok[k] = (idx < chunk && e < E2);
      if (ok[k]){
        r2[k] = rows2[e]; c2[k] = cols2[e]; v2[k] = vals2[e];
        sr2[k] = (e >= E) ? 1u : 0u;
      }
    }
#pragma unroll
    for (int k = 0; k < 2; ++k){
      if (ok[k]){
        int b = r2[k] >> 7;
        uint2 ent = make_uint2((uint32_t)(r2[k] & 127) | ((uint32_t)c2[k] << 7) | (sr2[k] << 24),
                               __float_as_uint(v2[k]));
        int sp = atomicAdd(&scnt[b], 1);
        if (sp < SDEPTH){
          stage[b][sp] = ent;
        } else {
          int pos = atomicAdd(&cursor[b * CPAD], 1);
          if (pos < BCAP) gbuf[(size_t)b * BCAP + pos] = ent;
          else overflow_add(r2[k], c2[k], (int)sr2[k], v2[k], H2, out);
        }
      }
    }
    __syncthreads();
    if (tid < NBUCK){
      int b = tid;
      if (scnt[b] >= SDEPTH){
        int pos = atomicAdd(&cursor[b * CPAD], SDEPTH);
#pragma unroll
        for (int i = 0; i < SDEPTH; ++i){
          uint2 ent = stage[b][i];
          if (pos + i < BCAP) gbuf[(size_t)b * BCAP + pos + i] = ent;
          else overflow_add((b << 7) | (int)(ent.x & 127u), (int)((ent.x >> 7) & 0x1FFFFu),
                            (int)(ent.x >> 24), __uint_as_float(ent.y), H2, out);
        }
        scnt[b] = 0;
      }
    }
    __syncthreads();
  }
  if (tid < NBUCK){
    int b = tid;
    int n = scnt[b]; if (n > SDEPTH) n = SDEPTH;
    if (n > 0){
      int pos = atomicAdd(&cursor[b * CPAD], n);
      for (int i = 0; i < n; ++i){
        uint2 ent = stage[b][i];
        if (pos + i < BCAP) gbuf[(size_t)b * BCAP + pos + i] = ent;
        else overflow_add((b << 7) | (int)(ent.x & 127u), (int)((ent.x >> 7) & 0x1FFFFu),
                          (int)(ent.x >> 24), __uint_as_float(ent.y), H2, out);
      }
    }
  }
}

// ---- accum4: (srel,row)-phased sort -> per-relation L2 working set 25.6MB; unroll-16 gather ----
template<bool LAST>
__global__ __launch_bounds__(512) void accum4_kernel(const uint2* __restrict__ gbuf,
                                                     int* __restrict__ cursor,
                                                     const uint16_t* __restrict__ H2,
                                                     float* __restrict__ out){
  __shared__ uint2 srt[BCAP];     // 36,864 B
  __shared__ int   cnt[2 * BROWS];  // 256 keys: key = srel*128 + rowlocal
  __shared__ int   pos[2 * BROWS];
  __shared__ int   cur[2 * BROWS];
  __shared__ int   entS;
  const int b = blockIdx.x;
  const int row0 = b * BROWS;
  const int tid = threadIdx.x;

  if (tid == 0){
    int e = cursor[b * CPAD]; if (e > BCAP) e = BCAP;
    entS = e;
  }
  if (tid < 2 * BROWS) cnt[tid] = 0;
  __syncthreads();
  const int entries = entS;
  if (tid == 0) cursor[b * CPAD] = 0;          // re-zero for next group (entS latched)
  const uint2* bbase = gbuf + (size_t)b * BCAP;

  // histogram over 256 keys (gbuf read 1)
  for (int i = tid; i < entries; i += 512){
    uint32_t x = bbase[i].x;
    atomicAdd(&cnt[((x >> 17) & 128u) | (x & 127u)], 1);   // (srel<<7) | rowlocal
  }
  __syncthreads();

  // exclusive prefix over 256 counts: wave 0, 4 counts/lane, shfl scan
  if (tid < 64){
    int a0 = cnt[4 * tid], a1 = cnt[4 * tid + 1], a2 = cnt[4 * tid + 2], a3 = cnt[4 * tid + 3];
    int s = a0 + a1 + a2 + a3;
#pragma unroll
    for (int d = 1; d < 64; d <<= 1){
      int t = __shfl_up(s, d);
      if (tid >= d) s += t;
    }
    int excl = s - (a0 + a1 + a2 + a3);
    pos[4 * tid] = excl;  cur[4 * tid] = excl;  excl += a0;
    pos[4 * tid + 1] = excl;  cur[4 * tid + 1] = excl;  excl += a1;
    pos[4 * tid + 2] = excl;  cur[4 * tid + 2] = excl;  excl += a2;
    pos[4 * tid + 3] = excl;  cur[4 * tid + 3] = excl;
  }
  __syncthreads();

  // reorder into (srel,row)-sorted LDS (gbuf read 2)
  for (int i = tid; i < entries; i += 512){
    uint2 e = bbase[i];
    int p = atomicAdd(&cur[((e.x >> 17) & 128u) | (e.x & 127u)], 1);
    srt[p] = e;
  }
  __syncthreads();

  // process: 8 waves x 16 rows; per row: s0 segment then s1 segment into one accumulator
  const int wave = tid >> 6, lane = tid & 63;
#pragma unroll
  for (int rr = 0; rr < 16; ++rr){
    int rl = wave * 16 + rr;
    int row = row0 + rl;
    if (row >= NN) break;
    float2 acc = *(const float2*)(out + (size_t)row * OO + lane * 2);
#pragma unroll
    for (int seg = 0; seg < 2; ++seg){
      int key = seg * BROWS + rl;
      int n  = cnt[key];
      int b0 = pos[key];
      const uint16_t* hsbase = H2 + (size_t)seg * (NN * OO);
      int k = 0;
      for (; k + 16 <= n; k += 16){
        float accx = 0.f, accy = 0.f;
#pragma unroll
        for (int j = 0; j < 16; ++j){
          uint2 e = srt[b0 + k + j];
          uint32_t q = ((const uint32_t*)(hsbase + (size_t)((e.x >> 7) & 0x1FFFFu) * OO))[lane];
          float v = __uint_as_float(e.y);
          accx += v * bf2f((uint16_t)(q & 0xFFFFu));
          accy += v * bf2f((uint16_t)(q >> 16));
        }
        acc.x += accx; acc.y += accy;
      }
      for (; k + 4 <= n; k += 4){
        float accx = 0.f, accy = 0.f;
#pragma unroll
        for (int j = 0; j < 4; ++j){
          uint2 e = srt[b0 + k + j];
          uint32_t q = ((const uint32_t*)(hsbase + (size_t)((e.x >> 7) & 0x1FFFFu) * OO))[lane];
          float v = __uint_as_float(e.y);
          accx += v * bf2f((uint16_t)(q & 0xFFFFu));
          accy += v * bf2f((uint16_t)(q >> 16));
        }
        acc.x += accx; acc.y += accy;
      }
      for (; k < n; ++k){
        uint2 e = srt[b0 + k];
        uint32_t q = ((const uint32_t*)(hsbase + (size_t)((e.x >> 7) & 0x1FFFFu) * OO))[lane];
        float v = __uint_as_float(e.y);
        acc.x += v * bf2f((uint16_t)(q & 0xFFFFu));
        acc.y += v * bf2f((uint16_t)(q >> 16));
      }
    }
    if (LAST){ acc.x = fmaxf(acc.x, 0.f); acc.y = fmaxf(acc.y, 0.f); }
    *(float2*)(out + (size_t)row * OO + lane * 2) = acc;
  }
}

// ======== fallback (R0/R2-validated path pieces, only if ws too small) ========
__global__ void cast_bf16_kernel(const float* __restrict__ in, uint16_t* __restrict__ out, int n4){
  int i = blockIdx.x * blockDim.x + threadIdx.x;
  if (i < n4){
    float4 v = ((const float4*)in)[i];
    ushort4 o;
    o.x = f2bf(v.x); o.y = f2bf(v.y); o.z = f2bf(v.z); o.w = f2bf(v.w);
    ((ushort4*)out)[i] = o;
  }
}

__global__ __launch_bounds__(256) void gemm_kernel(const uint16_t* __restrict__ X16,
                                                   const uint16_t* __restrict__ VtS,
                                                   uint16_t* __restrict__ H16){
  const int wave = threadIdx.x >> 6;
  const int lane = threadIdx.x & 63;
  const int lr = lane & 15, lk = lane >> 4;
  const int row0 = blockIdx.x * 64 + wave * 16;
  f32x4 acc[8];
#pragma unroll
  for (int t = 0; t < 8; ++t) acc[t] = (f32x4){0.f, 0.f, 0.f, 0.f};
  int arow = row0 + lr; if (arow >= NN) arow = NN - 1;
  const uint16_t* aptr = X16 + (size_t)arow * DD + lk * 8;
#pragma unroll
  for (int kb = 0; kb < DD; kb += 32){
    short8 a = *(const short8*)(aptr + kb);
#pragma unroll
    for (int t = 0; t < 8; ++t){
      short8 b = *(const short8*)(VtS + (size_t)(t * 16 + lr) * DD + kb + lk * 8);
      acc[t] = __builtin_amdgcn_mfma_f32_16x16x32_bf16(a, b, acc[t], 0, 0, 0);
    }
  }
#pragma unroll
  for (int t = 0; t < 8; ++t){
#pragma unroll
    for (int j = 0; j < 4; ++j){
      int r = row0 + lk * 4 + j;
      if (r < NN) H16[(size_t)r * OO + t * 16 + lr] = f2bf(acc[t][j]);
    }
  }
}

__global__ __launch_bounds__(256) void spmm_kernel(const int* __restrict__ rows,
                                                   const int* __restrict__ cols,
                                                   const float* __restrict__ vals,
                                                   const uint16_t* __restrict__ H16,
                                                   float* __restrict__ out, int E){
  const int lane = threadIdx.x & 63;
  const int gwave = (int)((blockIdx.x * blockDim.x + threadIdx.x) >> 6);
  const int nw = (gridDim.x * blockDim.x) >> 6;
  for (int base = gwave * 64; base < E; base += nw * 64){
    int cnt = E - base; if (cnt > 64) cnt = 64;
    int r = 0, c = 0; float v = 0.f;
    if (lane < cnt){
      r = rows[base + lane]; c = cols[base + lane]; v = vals[base + lane];
    }
    for (int k = 0; k < cnt; ++k){
      int rr = __shfl(r, k);
      int cc = __shfl(c, k);
      float vv = __shfl(v, k);
      uint32_t pair = *(const uint32_t*)(H16 + (size_t)cc * OO + lane * 2);
      float* dst = out + (size_t)rr * OO + lane * 2;
      unsafeAtomicAdd(dst,     vv * bf2f((uint16_t)(pair & 0xFFFFu)));
      unsafeAtomicAdd(dst + 1, vv * bf2f((uint16_t)(pair >> 16)));
    }
  }
}

__global__ void relu_kernel(float* __restrict__ out, int n4){
  int i = blockIdx.x * blockDim.x + threadIdx.x;
  if (i < n4){
    float4 v = ((float4*)out)[i];
    v.x = fmaxf(v.x, 0.f); v.y = fmaxf(v.y, 0.f);
    v.z = fmaxf(v.z, 0.f); v.w = fmaxf(v.w, 0.f);
    ((float4*)out)[i] = v;
  }
}
// =============================================================================

extern "C" void kernel_launch(void* const* d_in, const int* in_sizes, int n_in,
                              void* d_out, int out_size, void* d_ws, size_t ws_size,
                              hipStream_t stream){
  const float* features = (const float*)d_in[0];
  const int*   rows     = (const int*)d_in[1];
  const int*   cols     = (const int*)d_in[2];
  const float* vals     = (const float*)d_in[3];
  const float* W        = (const float*)d_in[4];
  const float* Wc       = (const float*)d_in[5];
  float* out = (float*)d_out;
  const int E = in_sizes[1] / NS;

  char* ws = (char*)d_ws;
  // ---- main layout ----
  uint16_t* Vt     = (uint16_t*)ws;                     //    262,144
  uint16_t* H2     = (uint16_t*)(ws + 262144);          // 51,200,000 (2 relations)
  int*      cursor = (int*)     (ws + 51462144);        //     50,048
  uint2*    gbuf   = (uint2*)   (ws + 51512192);        // 28,827,648 (782 x 4608 x 8B)
  const size_t NEEDED = 51512192 + (size_t)NBUCK * BCAP * 8;   // 80,339,840 < proven ws >= 90,262,144

  hipMemsetAsync(d_out, 0, (size_t)out_size * sizeof(float), stream);

  if (ws_size >= NEEDED){
    vt_kernel<<<NS * OO, DD, 0, stream>>>(W, Wc, Vt);
    hipMemsetAsync(cursor, 0, (size_t)NBUCK * CPAD * sizeof(int), stream);  // once; accum re-zeroes
    const int chunk  = (2 * E + 255) / 256;
    const int rounds = (chunk + 2047) / 2048;
    for (int g = 0; g < 4; ++g){
      gemm2_kernel<<<(NN + 63) / 64, 256, 0, stream>>>(
          features, Vt + (size_t)(2 * g) * OO * DD, H2);
      bin3_kernel<<<256, 1024, 0, stream>>>(
          rows + (size_t)(2 * g) * E, cols + (size_t)(2 * g) * E, vals + (size_t)(2 * g) * E,
          H2, cursor, gbuf, out, E, chunk, rounds);
      if (g == 3)
        accum4_kernel<true><<<NBUCK, 512, 0, stream>>>(gbuf, cursor, H2, out);
      else
        accum4_kernel<false><<<NBUCK, 512, 0, stream>>>(gbuf, cursor, H2, out);
    }
    return;
  }

  // ---- fallback: cast + per-relation gemm + atomic spmm (R0/R2-validated) ----
  uint16_t* X16 = (uint16_t*)ws;                        // 25,600,000
  uint16_t* VtF = (uint16_t*)(ws + 25600000);           //    262,144
  uint16_t* H16 = (uint16_t*)(ws + 25862144);           // 25,600,000
  cast_bf16_kernel<<<(NN * DD / 4 + 255) / 256, 256, 0, stream>>>(features, X16, NN * DD / 4);
  vt_kernel<<<NS * OO, DD, 0, stream>>>(W, Wc, VtF);
  for (int s = 0; s < NS; ++s){
    gemm_kernel<<<(NN + 63) / 64, 256, 0, stream>>>(X16, VtF + (size_t)s * DD * OO, H16);
    spmm_kernel<<<4096, 256, 0, stream>>>(rows + (size_t)s * E, cols + (size_t)s * E,
                                          vals + (size_t)s * E, H16, out, E);
  }
  relu_kernel<<<(NN * OO / 4 + 255) / 256, 256, 0, stream>>>(out, NN * OO / 4);
}

// Round 13
// 1022.392 us; speedup vs baseline: 1.0647x; 1.0647x over previous
//
#include <hip/hip_runtime.h>
#include <hip/hip_bf16.h>
#include <stdint.h>

#define NN 100000   // nodes
#define DD 128      // input dim
#define OO 128      // output dim
#define NS 8        // relations
#define NB 4        // bases

#define BROWS 64    // rows per bucket
#define NBUCK 1563  // ceil(NN/BROWS)
#define SDEPTH 8    // bin LDS staging depth per bucket (flush = 8 entries = 64B)
#define BCAP 2560   // per-bucket capacity, 2-relation group (mean 2048 + 11 sigma)
#define CPAD 16     // cursor padding (ints) = 64B per counter

typedef __attribute__((ext_vector_type(8))) short short8;
typedef __attribute__((ext_vector_type(4))) float f32x4;

__device__ __forceinline__ float bf2f(uint16_t u){
  union { uint32_t i; float f; } x; x.i = ((uint32_t)u) << 16; return x.f;
}
__device__ __forceinline__ uint16_t f2bf(float f){
  union { float f; uint32_t i; } x; x.f = f;
  uint32_t r = (x.i + 0x7FFFu + ((x.i >> 16) & 1u)) >> 16;  // RNE
  return (uint16_t)r;
}

// ---- effective per-relation weight, TRANSPOSED: Vt[s][o][d] = M_s[d][o] ----
// M_s[d,o] = sum_b W_comp[d&7, b] * W[b*128 + s*16 + (d>>3), o]  (validated R1-R12)
__global__ void vt_kernel(const float* __restrict__ W, const float* __restrict__ Wc,
                          uint16_t* __restrict__ Vt){
  int d  = threadIdx.x;
  int so = blockIdx.x;
  int s = so >> 7, o = so & 127;
  int wrow = s * 16 + (d >> 3);
  int wci  = (d & 7) * NB;
  float acc = 0.f;
#pragma unroll
  for (int b = 0; b < NB; ++b)
    acc += Wc[wci + b] * W[(b * DD + wrow) * OO + o];
  Vt[so * DD + d] = f2bf(acc);
}

// ---- gemm2: H_{s0}, H_{s0+1} = X @ M; reads f32 X once, casts in-register (R10-validated) ----
__global__ __launch_bounds__(256) void gemm2_kernel(const float* __restrict__ X,
                                                    const uint16_t* __restrict__ Vt2,
                                                    uint16_t* __restrict__ H2){
  const int wave = threadIdx.x >> 6;
  const int lane = threadIdx.x & 63;
  const int lr = lane & 15, lk = lane >> 4;
  const int row0 = blockIdx.x * 64 + wave * 16;

  int arow = row0 + lr; if (arow >= NN) arow = NN - 1;
  const float* ap = X + (size_t)arow * DD;
  short8 a[4];
#pragma unroll
  for (int kb = 0; kb < 4; ++kb){
    float4 f0 = *(const float4*)(ap + kb * 32 + lk * 8);
    float4 f1 = *(const float4*)(ap + kb * 32 + lk * 8 + 4);
    short8 t;
    t[0] = (short)f2bf(f0.x); t[1] = (short)f2bf(f0.y);
    t[2] = (short)f2bf(f0.z); t[3] = (short)f2bf(f0.w);
    t[4] = (short)f2bf(f1.x); t[5] = (short)f2bf(f1.y);
    t[6] = (short)f2bf(f1.z); t[7] = (short)f2bf(f1.w);
    a[kb] = t;
  }

  for (int j = 0; j < 2; ++j){
    f32x4 acc[8];
#pragma unroll
    for (int t = 0; t < 8; ++t) acc[t] = (f32x4){0.f, 0.f, 0.f, 0.f};
    const uint16_t* vb = Vt2 + (size_t)j * OO * DD;
#pragma unroll
    for (int kb = 0; kb < 4; ++kb){
#pragma unroll
      for (int t = 0; t < 8; ++t){
        short8 b = *(const short8*)(vb + (size_t)(t * 16 + lr) * DD + kb * 32 + lk * 8);
        acc[t] = __builtin_amdgcn_mfma_f32_16x16x32_bf16(a[kb], b, acc[t], 0, 0, 0);
      }
    }
    uint16_t* hs = H2 + (size_t)j * NN * OO;
#pragma unroll
    for (int t = 0; t < 8; ++t){
#pragma unroll
      for (int jj = 0; jj < 4; ++jj){
        int r = row0 + lk * 4 + jj;
        if (r < NN) hs[(size_t)r * OO + t * 16 + lr] = f2bf(acc[t][jj]);
      }
    }
  }
}

// entry encode: rowlocal[0:5], col[6:22], srel[23]
__device__ __noinline__ void overflow_add(int r, int c, int srel, float v,
                                          const uint16_t* __restrict__ H2,
                                          float* __restrict__ out){
  const uint16_t* h = H2 + (size_t)srel * NN * OO + (size_t)c * OO;
  float* dst = out + (size_t)r * OO;
  for (int d = 0; d < OO; ++d) unsafeAtomicAdd(dst + d, v * bf2f(h[d]));
}

// ---- bin4: multisplit 2 relations' edges into 1563 row-buckets; 2 edges/thread/round ----
__global__ __launch_bounds__(1024) void bin4_kernel(const int* __restrict__ rows2,
                                                    const int* __restrict__ cols2,
                                                    const float* __restrict__ vals2,
                                                    const uint16_t* __restrict__ H2,
                                                    int* __restrict__ cursor,
                                                    uint2* __restrict__ gbuf,
                                                    float* __restrict__ out,
                                                    int E, int chunk, int rounds){
  __shared__ uint2 stage[NBUCK][SDEPTH];   // 100,032 B
  __shared__ int   scnt[NBUCK];            //   6,252 B
  const int tid = threadIdx.x;
  const int E2 = 2 * E;
  for (int i = tid; i < NBUCK; i += 1024) scnt[i] = 0;
  __syncthreads();
  const int e0 = blockIdx.x * chunk;
  for (int rd = 0; rd < rounds; ++rd){
    int r2[2], c2[2]; float v2[2]; uint32_t sr2[2]; bool ok[2];
#pragma unroll
    for (int k = 0; k < 2; ++k){
      int idx = rd * 2048 + k * 1024 + tid;
      int e = e0 + idx;
      ok[k] = (idx < chunk && e < E2);
      if (ok[k]){
        r2[k] = rows2[e]; c2[k] = cols2[e]; v2[k] = vals2[e];
        sr2[k] = (e >= E) ? 1u : 0u;
      }
    }
#pragma unroll
    for (int k = 0; k < 2; ++k){
      if (ok[k]){
        int b = r2[k] >> 6;
        uint2 ent = make_uint2((uint32_t)(r2[k] & 63) | ((uint32_t)c2[k] << 6) | (sr2[k] << 23),
                               __float_as_uint(v2[k]));
        int sp = atomicAdd(&scnt[b], 1);
        if (sp < SDEPTH){
          stage[b][sp] = ent;
        } else {
          int pos = atomicAdd(&cursor[b * CPAD], 1);
          if (pos < BCAP) gbuf[(size_t)b * BCAP + pos] = ent;
          else overflow_add(r2[k], c2[k], (int)sr2[k], v2[k], H2, out);
        }
      }
    }
    __syncthreads();
    for (int b = tid; b < NBUCK; b += 1024){
      if (scnt[b] >= SDEPTH){
        int pos = atomicAdd(&cursor[b * CPAD], SDEPTH);
#pragma unroll
        for (int i = 0; i < SDEPTH; ++i){
          uint2 ent = stage[b][i];
          if (pos + i < BCAP) gbuf[(size_t)b * BCAP + pos + i] = ent;
          else overflow_add((b << 6) | (int)(ent.x & 63u), (int)((ent.x >> 6) & 0x1FFFFu),
                            (int)(ent.x >> 23), __uint_as_float(ent.y), H2, out);
        }
        scnt[b] = 0;
      }
    }
    __syncthreads();
  }
  for (int b = tid; b < NBUCK; b += 1024){
    int n = scnt[b]; if (n > SDEPTH) n = SDEPTH;
    if (n > 0){
      int pos = atomicAdd(&cursor[b * CPAD], n);
      for (int i = 0; i < n; ++i){
        uint2 ent = stage[b][i];
        if (pos + i < BCAP) gbuf[(size_t)b * BCAP + pos + i] = ent;
        else overflow_add((b << 6) | (int)(ent.x & 63u), (int)((ent.x >> 6) & 0x1FFFFu),
                          (int)(ent.x >> 23), __uint_as_float(ent.y), H2, out);
      }
    }
  }
}

// ---- accum5: 64-row buckets, 256-thread blocks (~7 blocks/CU = 28 waves/CU), row sort + unroll-8 gather ----
template<bool LAST>
__global__ __launch_bounds__(256) void accum5_kernel(const uint2* __restrict__ gbuf,
                                                     int* __restrict__ cursor,
                                                     const uint16_t* __restrict__ H2,
                                                     float* __restrict__ out){
  __shared__ uint2 srt[BCAP];     // 20,480 B
  __shared__ int   cnt[BROWS];
  __shared__ int   pos[BROWS];
  __shared__ int   cur[BROWS];
  __shared__ int   entS;
  const int b = blockIdx.x;
  const int row0 = b * BROWS;
  const int tid = threadIdx.x;

  if (tid == 0){
    int e = cursor[b * CPAD]; if (e > BCAP) e = BCAP;
    entS = e;
  }
  if (tid < BROWS) cnt[tid] = 0;
  __syncthreads();
  const int entries = entS;
  if (tid == 0) cursor[b * CPAD] = 0;          // re-zero for next group (entS latched)
  const uint2* bbase = gbuf + (size_t)b * BCAP;

  // histogram over 64 row-keys (gbuf read 1)
  for (int i = tid; i < entries; i += 256)
    atomicAdd(&cnt[bbase[i].x & 63u], 1);
  __syncthreads();

  // exclusive prefix over 64 counts: wave 0, 1 count/lane
  if (tid < 64){
    int a = cnt[tid];
    int s = a;
#pragma unroll
    for (int d = 1; d < 64; d <<= 1){
      int t = __shfl_up(s, d);
      if (tid >= d) s += t;
    }
    int excl = s - a;
    pos[tid] = excl;
    cur[tid] = excl;
  }
  __syncthreads();

  // reorder into row-sorted LDS (gbuf read 2)
  for (int i = tid; i < entries; i += 256){
    uint2 e = bbase[i];
    int p = atomicAdd(&cur[e.x & 63u], 1);
    srt[p] = e;
  }
  __syncthreads();

  // process: 4 waves x 16 rows; register float2 accumulation; one RMW of out per row
  const int wave = tid >> 6, lane = tid & 63;
#pragma unroll
  for (int rr = 0; rr < 16; ++rr){
    int rl = wave * 16 + rr;
    int row = row0 + rl;
    if (row >= NN) break;
    int n  = cnt[rl];
    int b0 = pos[rl];
    float2 acc = *(const float2*)(out + (size_t)row * OO + lane * 2);
    int k = 0;
    for (; k + 8 <= n; k += 8){
      float accx = 0.f, accy = 0.f;
#pragma unroll
      for (int j = 0; j < 8; ++j){
        uint2 e = srt[b0 + k + j];
        const uint16_t* h = H2 + (size_t)(e.x >> 23) * (NN * OO)
                               + (size_t)((e.x >> 6) & 0x1FFFFu) * OO;
        uint32_t q = ((const uint32_t*)h)[lane];
        float v = __uint_as_float(e.y);
        accx += v * bf2f((uint16_t)(q & 0xFFFFu));
        accy += v * bf2f((uint16_t)(q >> 16));
      }
      acc.x += accx; acc.y += accy;
    }
    for (; k < n; ++k){
      uint2 e = srt[b0 + k];
      const uint16_t* h = H2 + (size_t)(e.x >> 23) * (NN * OO)
                             + (size_t)((e.x >> 6) & 0x1FFFFu) * OO;
      uint32_t q = ((const uint32_t*)h)[lane];
      float v = __uint_as_float(e.y);
      acc.x += v * bf2f((uint16_t)(q & 0xFFFFu));
      acc.y += v * bf2f((uint16_t)(q >> 16));
    }
    if (LAST){ acc.x = fmaxf(acc.x, 0.f); acc.y = fmaxf(acc.y, 0.f); }
    *(float2*)(out + (size_t)row * OO + lane * 2) = acc;
  }
}

// ======== fallback (R0/R2-validated path pieces, only if ws too small) ========
__global__ void cast_bf16_kernel(const float* __restrict__ in, uint16_t* __restrict__ out, int n4){
  int i = blockIdx.x * blockDim.x + threadIdx.x;
  if (i < n4){
    float4 v = ((const float4*)in)[i];
    ushort4 o;
    o.x = f2bf(v.x); o.y = f2bf(v.y); o.z = f2bf(v.z); o.w = f2bf(v.w);
    ((ushort4*)out)[i] = o;
  }
}

__global__ __launch_bounds__(256) void gemm_kernel(const uint16_t* __restrict__ X16,
                                                   const uint16_t* __restrict__ VtS,
                                                   uint16_t* __restrict__ H16){
  const int wave = threadIdx.x >> 6;
  const int lane = threadIdx.x & 63;
  const int lr = lane & 15, lk = lane >> 4;
  const int row0 = blockIdx.x * 64 + wave * 16;
  f32x4 acc[8];
#pragma unroll
  for (int t = 0; t < 8; ++t) acc[t] = (f32x4){0.f, 0.f, 0.f, 0.f};
  int arow = row0 + lr; if (arow >= NN) arow = NN - 1;
  const uint16_t* aptr = X16 + (size_t)arow * DD + lk * 8;
#pragma unroll
  for (int kb = 0; kb < DD; kb += 32){
    short8 a = *(const short8*)(aptr + kb);
#pragma unroll
    for (int t = 0; t < 8; ++t){
      short8 b = *(const short8*)(VtS + (size_t)(t * 16 + lr) * DD + kb + lk * 8);
      acc[t] = __builtin_amdgcn_mfma_f32_16x16x32_bf16(a, b, acc[t], 0, 0, 0);
    }
  }
#pragma unroll
  for (int t = 0; t < 8; ++t){
#pragma unroll
    for (int j = 0; j < 4; ++j){
      int r = row0 + lk * 4 + j;
      if (r < NN) H16[(size_t)r * OO + t * 16 + lr] = f2bf(acc[t][j]);
    }
  }
}

__global__ __launch_bounds__(256) void spmm_kernel(const int* __restrict__ rows,
                                                   const int* __restrict__ cols,
                                                   const float* __restrict__ vals,
                                                   const uint16_t* __restrict__ H16,
                                                   float* __restrict__ out, int E){
  const int lane = threadIdx.x & 63;
  const int gwave = (int)((blockIdx.x * blockDim.x + threadIdx.x) >> 6);
  const int nw = (gridDim.x * blockDim.x) >> 6;
  for (int base = gwave * 64; base < E; base += nw * 64){
    int cnt = E - base; if (cnt > 64) cnt = 64;
    int r = 0, c = 0; float v = 0.f;
    if (lane < cnt){
      r = rows[base + lane]; c = cols[base + lane]; v = vals[base + lane];
    }
    for (int k = 0; k < cnt; ++k){
      int rr = __shfl(r, k);
      int cc = __shfl(c, k);
      float vv = __shfl(v, k);
      uint32_t pair = *(const uint32_t*)(H16 + (size_t)cc * OO + lane * 2);
      float* dst = out + (size_t)rr * OO + lane * 2;
      unsafeAtomicAdd(dst,     vv * bf2f((uint16_t)(pair & 0xFFFFu)));
      unsafeAtomicAdd(dst + 1, vv * bf2f((uint16_t)(pair >> 16)));
    }
  }
}

__global__ void relu_kernel(float* __restrict__ out, int n4){
  int i = blockIdx.x * blockDim.x + threadIdx.x;
  if (i < n4){
    float4 v = ((float4*)out)[i];
    v.x = fmaxf(v.x, 0.f); v.y = fmaxf(v.y, 0.f);
    v.z = fmaxf(v.z, 0.f); v.w = fmaxf(v.w, 0.f);
    ((float4*)out)[i] = v;
  }
}
// =============================================================================

extern "C" void kernel_launch(void* const* d_in, const int* in_sizes, int n_in,
                              void* d_out, int out_size, void* d_ws, size_t ws_size,
                              hipStream_t stream){
  const float* features = (const float*)d_in[0];
  const int*   rows     = (const int*)d_in[1];
  const int*   cols     = (const int*)d_in[2];
  const float* vals     = (const float*)d_in[3];
  const float* W        = (const float*)d_in[4];
  const float* Wc       = (const float*)d_in[5];
  float* out = (float*)d_out;
  const int E = in_sizes[1] / NS;

  char* ws = (char*)d_ws;
  // ---- main layout ----
  uint16_t* Vt     = (uint16_t*)ws;                     //    262,144
  uint16_t* H2     = (uint16_t*)(ws + 262144);          // 51,200,000 (2 relations)
  int*      cursor = (int*)     (ws + 51462144);        //    100,032 (1563 x 64B padded)
  uint2*    gbuf   = (uint2*)   (ws + 51562176);        // 32,010,240 (1563 x 2560 x 8B)
  const size_t NEEDED = 51562176 + (size_t)NBUCK * BCAP * 8;   // 83,572,416 < proven ws >= 90,262,144

  hipMemsetAsync(d_out, 0, (size_t)out_size * sizeof(float), stream);

  if (ws_size >= NEEDED){
    vt_kernel<<<NS * OO, DD, 0, stream>>>(W, Wc, Vt);
    hipMemsetAsync(cursor, 0, (size_t)NBUCK * CPAD * sizeof(int), stream);  // once; accum re-zeroes
    const int chunk  = (2 * E + 255) / 256;
    const int rounds = (chunk + 2047) / 2048;
    for (int g = 0; g < 4; ++g){
      gemm2_kernel<<<(NN + 63) / 64, 256, 0, stream>>>(
          features, Vt + (size_t)(2 * g) * OO * DD, H2);
      bin4_kernel<<<256, 1024, 0, stream>>>(
          rows + (size_t)(2 * g) * E, cols + (size_t)(2 * g) * E, vals + (size_t)(2 * g) * E,
          H2, cursor, gbuf, out, E, chunk, rounds);
      if (g == 3)
        accum5_kernel<true><<<NBUCK, 256, 0, stream>>>(gbuf, cursor, H2, out);
      else
        accum5_kernel<false><<<NBUCK, 256, 0, stream>>>(gbuf, cursor, H2, out);
    }
    return;
  }

  // ---- fallback: cast + per-relation gemm + atomic spmm (R0/R2-validated) ----
  uint16_t* X16 = (uint16_t*)ws;                        // 25,600,000
  uint16_t* VtF = (uint16_t*)(ws + 25600000);           //    262,144
  uint16_t* H16 = (uint16_t*)(ws + 25862144);           // 25,600,000
  cast_bf16_kernel<<<(NN * DD / 4 + 255) / 256, 256, 0, stream>>>(features, X16, NN * DD / 4);
  vt_kernel<<<NS * OO, DD, 0, stream>>>(W, Wc, VtF);
  for (int s = 0; s < NS; ++s){
    gemm_kernel<<<(NN + 63) / 64, 256, 0, stream>>>(X16, VtF + (size_t)s * DD * OO, H16);
    spmm_kernel<<<4096, 256, 0, stream>>>(rows + (size_t)s * E, cols + (size_t)s * E,
                                          vals + (size_t)s * E, H16, out, E);
  }
  relu_kernel<<<(NN * OO / 4 + 255) / 256, 256, 0, stream>>>(out, NN * OO / 4);
}

// Round 14
// 991.615 us; speedup vs baseline: 1.0977x; 1.0310x over previous
//
#include <hip/hip_runtime.h>
#include <hip/hip_bf16.h>
#include <stdint.h>

#define NN 100000   // nodes
#define DD 128      // input dim
#define OO 128      // output dim
#define NS 8        // relations
#define NB 4        // bases

#define BROWS 64    // rows per bucket
#define NBUCK 1563  // ceil(NN/BROWS)
#define SDEPTH 12   // bin LDS staging depth per bucket (LDS 156.3KB, spills ~1e-5/bucket/round)
#define BCAP 2560   // per-bucket capacity, 2-relation group (mean 2048 + 11 sigma)
#define CPAD 16     // cursor padding (ints) = 64B per counter

typedef __attribute__((ext_vector_type(8))) short short8;
typedef __attribute__((ext_vector_type(4))) float f32x4;

__device__ __forceinline__ float bf2f(uint16_t u){
  union { uint32_t i; float f; } x; x.i = ((uint32_t)u) << 16; return x.f;
}
__device__ __forceinline__ uint16_t f2bf(float f){
  union { float f; uint32_t i; } x; x.f = f;
  uint32_t r = (x.i + 0x7FFFu + ((x.i >> 16) & 1u)) >> 16;  // RNE
  return (uint16_t)r;
}

// ---- effective per-relation weight, TRANSPOSED: Vt[s][o][d] = M_s[d][o] ----
// M_s[d,o] = sum_b W_comp[d&7, b] * W[b*128 + s*16 + (d>>3), o]  (validated R1-R13)
__global__ void vt_kernel(const float* __restrict__ W, const float* __restrict__ Wc,
                          uint16_t* __restrict__ Vt){
  int d  = threadIdx.x;
  int so = blockIdx.x;
  int s = so >> 7, o = so & 127;
  int wrow = s * 16 + (d >> 3);
  int wci  = (d & 7) * NB;
  float acc = 0.f;
#pragma unroll
  for (int b = 0; b < NB; ++b)
    acc += Wc[wci + b] * W[(b * DD + wrow) * OO + o];
  Vt[so * DD + d] = f2bf(acc);
}

// ---- gemm2: H_{s0}, H_{s0+1} = X @ M; reads f32 X once, casts in-register (R10-validated) ----
__global__ __launch_bounds__(256) void gemm2_kernel(const float* __restrict__ X,
                                                    const uint16_t* __restrict__ Vt2,
                                                    uint16_t* __restrict__ H2){
  const int wave = threadIdx.x >> 6;
  const int lane = threadIdx.x & 63;
  const int lr = lane & 15, lk = lane >> 4;
  const int row0 = blockIdx.x * 64 + wave * 16;

  int arow = row0 + lr; if (arow >= NN) arow = NN - 1;
  const float* ap = X + (size_t)arow * DD;
  short8 a[4];
#pragma unroll
  for (int kb = 0; kb < 4; ++kb){
    float4 f0 = *(const float4*)(ap + kb * 32 + lk * 8);
    float4 f1 = *(const float4*)(ap + kb * 32 + lk * 8 + 4);
    short8 t;
    t[0] = (short)f2bf(f0.x); t[1] = (short)f2bf(f0.y);
    t[2] = (short)f2bf(f0.z); t[3] = (short)f2bf(f0.w);
    t[4] = (short)f2bf(f1.x); t[5] = (short)f2bf(f1.y);
    t[6] = (short)f2bf(f1.z); t[7] = (short)f2bf(f1.w);
    a[kb] = t;
  }

  for (int j = 0; j < 2; ++j){
    f32x4 acc[8];
#pragma unroll
    for (int t = 0; t < 8; ++t) acc[t] = (f32x4){0.f, 0.f, 0.f, 0.f};
    const uint16_t* vb = Vt2 + (size_t)j * OO * DD;
#pragma unroll
    for (int kb = 0; kb < 4; ++kb){
#pragma unroll
      for (int t = 0; t < 8; ++t){
        short8 b = *(const short8*)(vb + (size_t)(t * 16 + lr) * DD + kb * 32 + lk * 8);
        acc[t] = __builtin_amdgcn_mfma_f32_16x16x32_bf16(a[kb], b, acc[t], 0, 0, 0);
      }
    }
    uint16_t* hs = H2 + (size_t)j * NN * OO;
#pragma unroll
    for (int t = 0; t < 8; ++t){
#pragma unroll
      for (int jj = 0; jj < 4; ++jj){
        int r = row0 + lk * 4 + jj;
        if (r < NN) hs[(size_t)r * OO + t * 16 + lr] = f2bf(acc[t][jj]);
      }
    }
  }
}

// entry encode: rowlocal[0:5], col[6:22], srel[23]
__device__ __noinline__ void overflow_add(int r, int c, int srel, float v,
                                          const uint16_t* __restrict__ H2,
                                          float* __restrict__ out){
  const uint16_t* h = H2 + (size_t)srel * NN * OO + (size_t)c * OO;
  float* dst = out + (size_t)r * OO;
  for (int d = 0; d < OO; ++d) unsafeAtomicAdd(dst + d, v * bf2f(h[d]));
}

// ---- bin5: multisplit, 4 edges/thread/round (7 rounds, 14 barriers), SDEPTH 12 ----
__global__ __launch_bounds__(1024) void bin5_kernel(const int* __restrict__ rows2,
                                                    const int* __restrict__ cols2,
                                                    const float* __restrict__ vals2,
                                                    const uint16_t* __restrict__ H2,
                                                    int* __restrict__ cursor,
                                                    uint2* __restrict__ gbuf,
                                                    float* __restrict__ out,
                                                    int E, int chunk, int rounds){
  __shared__ uint2 stage[NBUCK][SDEPTH];   // 150,048 B
  __shared__ int   scnt[NBUCK];            //   6,252 B
  const int tid = threadIdx.x;
  const int E2 = 2 * E;
  for (int i = tid; i < NBUCK; i += 1024) scnt[i] = 0;
  __syncthreads();
  const int e0 = blockIdx.x * chunk;
  for (int rd = 0; rd < rounds; ++rd){
    int r2[4], c2[4]; float v2[4]; uint32_t sr2[4]; bool ok[4];
#pragma unroll
    for (int k = 0; k < 4; ++k){
      int idx = rd * 4096 + k * 1024 + tid;
      int e = e0 + idx;
      ok[k] = (idx < chunk && e < E2);
      if (ok[k]){
        r2[k] = rows2[e]; c2[k] = cols2[e]; v2[k] = vals2[e];
        sr2[k] = (e >= E) ? 1u : 0u;
      }
    }
#pragma unroll
    for (int k = 0; k < 4; ++k){
      if (ok[k]){
        int b = r2[k] >> 6;
        uint2 ent = make_uint2((uint32_t)(r2[k] & 63) | ((uint32_t)c2[k] << 6) | (sr2[k] << 23),
                               __float_as_uint(v2[k]));
        int sp = atomicAdd(&scnt[b], 1);
        if (sp < SDEPTH){
          stage[b][sp] = ent;
        } else {                               // rare spill: direct to gbuf
          int pos = atomicAdd(&cursor[b * CPAD], 1);
          if (pos < BCAP) gbuf[(size_t)b * BCAP + pos] = ent;
          else overflow_add(r2[k], c2[k], (int)sr2[k], v2[k], H2, out);
        }
      }
    }
    __syncthreads();
    for (int b = tid; b < NBUCK; b += 1024){
      if (scnt[b] >= SDEPTH){
        int pos = atomicAdd(&cursor[b * CPAD], SDEPTH);
#pragma unroll
        for (int i = 0; i < SDEPTH; ++i){
          uint2 ent = stage[b][i];
          if (pos + i < BCAP) gbuf[(size_t)b * BCAP + pos + i] = ent;
          else overflow_add((b << 6) | (int)(ent.x & 63u), (int)((ent.x >> 6) & 0x1FFFFu),
                            (int)(ent.x >> 23), __uint_as_float(ent.y), H2, out);
        }
        scnt[b] = 0;
      }
    }
    __syncthreads();
  }
  for (int b = tid; b < NBUCK; b += 1024){
    int n = scnt[b]; if (n > SDEPTH) n = SDEPTH;
    if (n > 0){
      int pos = atomicAdd(&cursor[b * CPAD], n);
      for (int i = 0; i < n; ++i){
        uint2 ent = stage[b][i];
        if (pos + i < BCAP) gbuf[(size_t)b * BCAP + pos + i] = ent;
        else overflow_add((b << 6) | (int)(ent.x & 63u), (int)((ent.x >> 6) & 0x1FFFFu),
                          (int)(ent.x >> 23), __uint_as_float(ent.y), H2, out);
      }
    }
  }
}

// ---- accum5: 64-row buckets, 256-thread blocks, row sort + unroll-8 register gather (R13-validated) ----
template<bool LAST>
__global__ __launch_bounds__(256) void accum5_kernel(const uint2* __restrict__ gbuf,
                                                     int* __restrict__ cursor,
                                                     const uint16_t* __restrict__ H2,
                                                     float* __restrict__ out){
  __shared__ uint2 srt[BCAP];     // 20,480 B
  __shared__ int   cnt[BROWS];
  __shared__ int   pos[BROWS];
  __shared__ int   cur[BROWS];
  __shared__ int   entS;
  const int b = blockIdx.x;
  const int row0 = b * BROWS;
  const int tid = threadIdx.x;

  if (tid == 0){
    int e = cursor[b * CPAD]; if (e > BCAP) e = BCAP;
    entS = e;
  }
  if (tid < BROWS) cnt[tid] = 0;
  __syncthreads();
  const int entries = entS;
  if (tid == 0) cursor[b * CPAD] = 0;          // re-zero for next group (entS latched)
  const uint2* bbase = gbuf + (size_t)b * BCAP;

  // histogram over 64 row-keys (gbuf read 1)
  for (int i = tid; i < entries; i += 256)
    atomicAdd(&cnt[bbase[i].x & 63u], 1);
  __syncthreads();

  // exclusive prefix over 64 counts: wave 0, 1 count/lane
  if (tid < 64){
    int a = cnt[tid];
    int s = a;
#pragma unroll
    for (int d = 1; d < 64; d <<= 1){
      int t = __shfl_up(s, d);
      if (tid >= d) s += t;
    }
    int excl = s - a;
    pos[tid] = excl;
    cur[tid] = excl;
  }
  __syncthreads();

  // reorder into row-sorted LDS (gbuf read 2)
  for (int i = tid; i < entries; i += 256){
    uint2 e = bbase[i];
    int p = atomicAdd(&cur[e.x & 63u], 1);
    srt[p] = e;
  }
  __syncthreads();

  // process: 4 waves x 16 rows; register float2 accumulation; one RMW of out per row
  const int wave = tid >> 6, lane = tid & 63;
#pragma unroll
  for (int rr = 0; rr < 16; ++rr){
    int rl = wave * 16 + rr;
    int row = row0 + rl;
    if (row >= NN) break;
    int n  = cnt[rl];
    int b0 = pos[rl];
    float2 acc = *(const float2*)(out + (size_t)row * OO + lane * 2);
    int k = 0;
    for (; k + 8 <= n; k += 8){
      float accx = 0.f, accy = 0.f;
#pragma unroll
      for (int j = 0; j < 8; ++j){
        uint2 e = srt[b0 + k + j];
        const uint16_t* h = H2 + (size_t)(e.x >> 23) * (NN * OO)
                               + (size_t)((e.x >> 6) & 0x1FFFFu) * OO;
        uint32_t q = ((const uint32_t*)h)[lane];
        float v = __uint_as_float(e.y);
        accx += v * bf2f((uint16_t)(q & 0xFFFFu));
        accy += v * bf2f((uint16_t)(q >> 16));
      }
      acc.x += accx; acc.y += accy;
    }
    for (; k < n; ++k){
      uint2 e = srt[b0 + k];
      const uint16_t* h = H2 + (size_t)(e.x >> 23) * (NN * OO)
                             + (size_t)((e.x >> 6) & 0x1FFFFu) * OO;
      uint32_t q = ((const uint32_t*)h)[lane];
      float v = __uint_as_float(e.y);
      acc.x += v * bf2f((uint16_t)(q & 0xFFFFu));
      acc.y += v * bf2f((uint16_t)(q >> 16));
    }
    if (LAST){ acc.x = fmaxf(acc.x, 0.f); acc.y = fmaxf(acc.y, 0.f); }
    *(float2*)(out + (size_t)row * OO + lane * 2) = acc;
  }
}

// ======== fallback (R0/R2-validated path pieces, only if ws too small) ========
__global__ void cast_bf16_kernel(const float* __restrict__ in, uint16_t* __restrict__ out, int n4){
  int i = blockIdx.x * blockDim.x + threadIdx.x;
  if (i < n4){
    float4 v = ((const float4*)in)[i];
    ushort4 o;
    o.x = f2bf(v.x); o.y = f2bf(v.y); o.z = f2bf(v.z); o.w = f2bf(v.w);
    ((ushort4*)out)[i] = o;
  }
}

__global__ __launch_bounds__(256) void gemm_kernel(const uint16_t* __restrict__ X16,
                                                   const uint16_t* __restrict__ VtS,
                                                   uint16_t* __restrict__ H16){
  const int wave = threadIdx.x >> 6;
  const int lane = threadIdx.x & 63;
  const int lr = lane & 15, lk = lane >> 4;
  const int row0 = blockIdx.x * 64 + wave * 16;
  f32x4 acc[8];
#pragma unroll
  for (int t = 0; t < 8; ++t) acc[t] = (f32x4){0.f, 0.f, 0.f, 0.f};
  int arow = row0 + lr; if (arow >= NN) arow = NN - 1;
  const uint16_t* aptr = X16 + (size_t)arow * DD + lk * 8;
#pragma unroll
  for (int kb = 0; kb < DD; kb += 32){
    short8 a = *(const short8*)(aptr + kb);
#pragma unroll
    for (int t = 0; t < 8; ++t){
      short8 b = *(const short8*)(VtS + (size_t)(t * 16 + lr) * DD + kb + lk * 8);
      acc[t] = __builtin_amdgcn_mfma_f32_16x16x32_bf16(a, b, acc[t], 0, 0, 0);
    }
  }
#pragma unroll
  for (int t = 0; t < 8; ++t){
#pragma unroll
    for (int j = 0; j < 4; ++j){
      int r = row0 + lk * 4 + j;
      if (r < NN) H16[(size_t)r * OO + t * 16 + lr] = f2bf(acc[t][j]);
    }
  }
}

__global__ __launch_bounds__(256) void spmm_kernel(const int* __restrict__ rows,
                                                   const int* __restrict__ cols,
                                                   const float* __restrict__ vals,
                                                   const uint16_t* __restrict__ H16,
                                                   float* __restrict__ out, int E){
  const int lane = threadIdx.x & 63;
  const int gwave = (int)((blockIdx.x * blockDim.x + threadIdx.x) >> 6);
  const int nw = (gridDim.x * blockDim.x) >> 6;
  for (int base = gwave * 64; base < E; base += nw * 64){
    int cnt = E - base; if (cnt > 64) cnt = 64;
    int r = 0, c = 0; float v = 0.f;
    if (lane < cnt){
      r = rows[base + lane]; c = cols[base + lane]; v = vals[base + lane];
    }
    for (int k = 0; k < cnt; ++k){
      int rr = __shfl(r, k);
      int cc = __shfl(c, k);
      float vv = __shfl(v, k);
      uint32_t pair = *(const uint32_t*)(H16 + (size_t)cc * OO + lane * 2);
      float* dst = out + (size_t)rr * OO + lane * 2;
      unsafeAtomicAdd(dst,     vv * bf2f((uint16_t)(pair & 0xFFFFu)));
      unsafeAtomicAdd(dst + 1, vv * bf2f((uint16_t)(pair >> 16)));
    }
  }
}

__global__ void relu_kernel(float* __restrict__ out, int n4){
  int i = blockIdx.x * blockDim.x + threadIdx.x;
  if (i < n4){
    float4 v = ((float4*)out)[i];
    v.x = fmaxf(v.x, 0.f); v.y = fmaxf(v.y, 0.f);
    v.z = fmaxf(v.z, 0.f); v.w = fmaxf(v.w, 0.f);
    ((float4*)out)[i] = v;
  }
}
// =============================================================================

extern "C" void kernel_launch(void* const* d_in, const int* in_sizes, int n_in,
                              void* d_out, int out_size, void* d_ws, size_t ws_size,
                              hipStream_t stream){
  const float* features = (const float*)d_in[0];
  const int*   rows     = (const int*)d_in[1];
  const int*   cols     = (const int*)d_in[2];
  const float* vals     = (const float*)d_in[3];
  const float* W        = (const float*)d_in[4];
  const float* Wc       = (const float*)d_in[5];
  float* out = (float*)d_out;
  const int E = in_sizes[1] / NS;

  char* ws = (char*)d_ws;
  // ---- main layout ----
  uint16_t* Vt     = (uint16_t*)ws;                     //    262,144
  uint16_t* H2     = (uint16_t*)(ws + 262144);          // 51,200,000 (2 relations)
  int*      cursor = (int*)     (ws + 51462144);        //    100,032 (1563 x 64B padded)
  uint2*    gbuf   = (uint2*)   (ws + 51562176);        // 32,010,240 (1563 x 2560 x 8B)
  const size_t NEEDED = 51562176 + (size_t)NBUCK * BCAP * 8;   // 83,572,416 < proven ws >= 90,262,144

  hipMemsetAsync(d_out, 0, (size_t)out_size * sizeof(float), stream);

  if (ws_size >= NEEDED){
    vt_kernel<<<NS * OO, DD, 0, stream>>>(W, Wc, Vt);
    hipMemsetAsync(cursor, 0, (size_t)NBUCK * CPAD * sizeof(int), stream);  // once; accum re-zeroes
    const int chunk  = (2 * E + 255) / 256;
    const int rounds = (chunk + 4095) / 4096;
    for (int g = 0; g < 4; ++g){
      gemm2_kernel<<<(NN + 63) / 64, 256, 0, stream>>>(
          features, Vt + (size_t)(2 * g) * OO * DD, H2);
      bin5_kernel<<<256, 1024, 0, stream>>>(
          rows + (size_t)(2 * g) * E, cols + (size_t)(2 * g) * E, vals + (size_t)(2 * g) * E,
          H2, cursor, gbuf, out, E, chunk, rounds);
      if (g == 3)
        accum5_kernel<true><<<NBUCK, 256, 0, stream>>>(gbuf, cursor, H2, out);
      else
        accum5_kernel<false><<<NBUCK, 256, 0, stream>>>(gbuf, cursor, H2, out);
    }
    return;
  }

  // ---- fallback: cast + per-relation gemm + atomic spmm (R0/R2-validated) ----
  uint16_t* X16 = (uint16_t*)ws;                        // 25,600,000
  uint16_t* VtF = (uint16_t*)(ws + 25600000);           //    262,144
  uint16_t* H16 = (uint16_t*)(ws + 25862144);           // 25,600,000
  cast_bf16_kernel<<<(NN * DD / 4 + 255) / 256, 256, 0, stream>>>(features, X16, NN * DD / 4);
  vt_kernel<<<NS * OO, DD, 0, stream>>>(W, Wc, VtF);
  for (int s = 0; s < NS; ++s){
    gemm_kernel<<<(NN + 63) / 64, 256, 0, stream>>>(X16, VtF + (size_t)s * DD * OO, H16);
    spmm_kernel<<<4096, 256, 0, stream>>>(rows + (size_t)s * E, cols + (size_t)s * E,
                                          vals + (size_t)s * E, H16, out, E);
  }
  relu_kernel<<<(NN * OO / 4 + 255) / 256, 256, 0, stream>>>(out, NN * OO / 4);
}

// Round 15
// 968.672 us; speedup vs baseline: 1.1237x; 1.0237x over previous
//
#include <hip/hip_runtime.h>
#include <hip/hip_bf16.h>
#include <stdint.h>

#define NN 100000   // nodes
#define DD 128      // input dim
#define OO 128      // output dim
#define NS 8        // relations
#define NB 4        // bases

#define BROWS 64    // rows per bucket
#define NBUCK 1563  // ceil(NN/BROWS)
#define SDEPTH 12   // bin LDS staging depth per bucket
#define BCAP 2560   // per-bucket capacity, 2-relation group (mean 2048 + 11 sigma)
#define CPAD 16     // cursor padding (ints) = 64B per counter
#define EPT 8       // bin: edges per thread per round

typedef __attribute__((ext_vector_type(8))) short short8;
typedef __attribute__((ext_vector_type(4))) float f32x4;

__device__ __forceinline__ float bf2f(uint16_t u){
  union { uint32_t i; float f; } x; x.i = ((uint32_t)u) << 16; return x.f;
}
__device__ __forceinline__ uint16_t f2bf(float f){
  union { float f; uint32_t i; } x; x.f = f;
  uint32_t r = (x.i + 0x7FFFu + ((x.i >> 16) & 1u)) >> 16;  // RNE
  return (uint16_t)r;
}

// ---- effective per-relation weight, TRANSPOSED: Vt[s][o][d] = M_s[d][o] ----
// M_s[d,o] = sum_b W_comp[d&7, b] * W[b*128 + s*16 + (d>>3), o]  (validated R1-R14)
__global__ void vt_kernel(const float* __restrict__ W, const float* __restrict__ Wc,
                          uint16_t* __restrict__ Vt){
  int d  = threadIdx.x;
  int so = blockIdx.x;
  int s = so >> 7, o = so & 127;
  int wrow = s * 16 + (d >> 3);
  int wci  = (d & 7) * NB;
  float acc = 0.f;
#pragma unroll
  for (int b = 0; b < NB; ++b)
    acc += Wc[wci + b] * W[(b * DD + wrow) * OO + o];
  Vt[so * DD + d] = f2bf(acc);
}

// ---- gemm2: H_{s0}, H_{s0+1} = X @ M; reads f32 X once, casts in-register (R10-validated) ----
__global__ __launch_bounds__(256) void gemm2_kernel(const float* __restrict__ X,
                                                    const uint16_t* __restrict__ Vt2,
                                                    uint16_t* __restrict__ H2){
  const int wave = threadIdx.x >> 6;
  const int lane = threadIdx.x & 63;
  const int lr = lane & 15, lk = lane >> 4;
  const int row0 = blockIdx.x * 64 + wave * 16;

  int arow = row0 + lr; if (arow >= NN) arow = NN - 1;
  const float* ap = X + (size_t)arow * DD;
  short8 a[4];
#pragma unroll
  for (int kb = 0; kb < 4; ++kb){
    float4 f0 = *(const float4*)(ap + kb * 32 + lk * 8);
    float4 f1 = *(const float4*)(ap + kb * 32 + lk * 8 + 4);
    short8 t;
    t[0] = (short)f2bf(f0.x); t[1] = (short)f2bf(f0.y);
    t[2] = (short)f2bf(f0.z); t[3] = (short)f2bf(f0.w);
    t[4] = (short)f2bf(f1.x); t[5] = (short)f2bf(f1.y);
    t[6] = (short)f2bf(f1.z); t[7] = (short)f2bf(f1.w);
    a[kb] = t;
  }

  for (int j = 0; j < 2; ++j){
    f32x4 acc[8];
#pragma unroll
    for (int t = 0; t < 8; ++t) acc[t] = (f32x4){0.f, 0.f, 0.f, 0.f};
    const uint16_t* vb = Vt2 + (size_t)j * OO * DD;
#pragma unroll
    for (int kb = 0; kb < 4; ++kb){
#pragma unroll
      for (int t = 0; t < 8; ++t){
        short8 b = *(const short8*)(vb + (size_t)(t * 16 + lr) * DD + kb * 32 + lk * 8);
        acc[t] = __builtin_amdgcn_mfma_f32_16x16x32_bf16(a[kb], b, acc[t], 0, 0, 0);
      }
    }
    uint16_t* hs = H2 + (size_t)j * NN * OO;
#pragma unroll
    for (int t = 0; t < 8; ++t){
#pragma unroll
      for (int jj = 0; jj < 4; ++jj){
        int r = row0 + lk * 4 + jj;
        if (r < NN) hs[(size_t)r * OO + t * 16 + lr] = f2bf(acc[t][jj]);
      }
    }
  }
}

// entry encode: rowlocal[0:5], col[6:22], srel[23]
__device__ __noinline__ void overflow_add(int r, int c, int srel, float v,
                                          const uint16_t* __restrict__ H2,
                                          float* __restrict__ out){
  const uint16_t* h = H2 + (size_t)srel * NN * OO + (size_t)c * OO;
  float* dst = out + (size_t)r * OO;
  for (int d = 0; d < OO; ++d) unsafeAtomicAdd(dst + d, v * bf2f(h[d]));
}

// ---- bin6: multisplit, 8 edges/thread/round (2 rounds, 4 barriers), SDEPTH 12 ----
__global__ __launch_bounds__(1024) void bin6_kernel(const int* __restrict__ rows2,
                                                    const int* __restrict__ cols2,
                                                    const float* __restrict__ vals2,
                                                    const uint16_t* __restrict__ H2,
                                                    int* __restrict__ cursor,
                                                    uint2* __restrict__ gbuf,
                                                    float* __restrict__ out,
                                                    int E, int chunk, int rounds){
  __shared__ uint2 stage[NBUCK][SDEPTH];   // 150,048 B
  __shared__ int   scnt[NBUCK];            //   6,252 B
  const int tid = threadIdx.x;
  const int E2 = 2 * E;
  for (int i = tid; i < NBUCK; i += 1024) scnt[i] = 0;
  __syncthreads();
  const int e0 = blockIdx.x * chunk;
  for (int rd = 0; rd < rounds; ++rd){
    int r2[EPT], c2[EPT]; float v2[EPT]; uint32_t sr2[EPT]; bool ok[EPT];
#pragma unroll
    for (int k = 0; k < EPT; ++k){
      int idx = (rd * EPT + k) * 1024 + tid;
      int e = e0 + idx;
      ok[k] = (idx < chunk && e < E2);
      if (ok[k]){
        r2[k] = rows2[e]; c2[k] = cols2[e]; v2[k] = vals2[e];
        sr2[k] = (e >= E) ? 1u : 0u;
      }
    }
#pragma unroll
    for (int k = 0; k < EPT; ++k){
      if (ok[k]){
        int b = r2[k] >> 6;
        uint2 ent = make_uint2((uint32_t)(r2[k] & 63) | ((uint32_t)c2[k] << 6) | (sr2[k] << 23),
                               __float_as_uint(v2[k]));
        int sp = atomicAdd(&scnt[b], 1);
        if (sp < SDEPTH){
          stage[b][sp] = ent;
        } else {                               // rare spill: direct to gbuf
          int pos = atomicAdd(&cursor[b * CPAD], 1);
          if (pos < BCAP) gbuf[(size_t)b * BCAP + pos] = ent;
          else overflow_add(r2[k], c2[k], (int)sr2[k], v2[k], H2, out);
        }
      }
    }
    __syncthreads();
    for (int b = tid; b < NBUCK; b += 1024){
      if (scnt[b] >= SDEPTH){
        int pos = atomicAdd(&cursor[b * CPAD], SDEPTH);
#pragma unroll
        for (int i = 0; i < SDEPTH; ++i){
          uint2 ent = stage[b][i];
          if (pos + i < BCAP) gbuf[(size_t)b * BCAP + pos + i] = ent;
          else overflow_add((b << 6) | (int)(ent.x & 63u), (int)((ent.x >> 6) & 0x1FFFFu),
                            (int)(ent.x >> 23), __uint_as_float(ent.y), H2, out);
        }
        scnt[b] = 0;
      }
    }
    __syncthreads();
  }
  for (int b = tid; b < NBUCK; b += 1024){
    int n = scnt[b]; if (n > SDEPTH) n = SDEPTH;
    if (n > 0){
      int pos = atomicAdd(&cursor[b * CPAD], n);
      for (int i = 0; i < n; ++i){
        uint2 ent = stage[b][i];
        if (pos + i < BCAP) gbuf[(size_t)b * BCAP + pos + i] = ent;
        else overflow_add((b << 6) | (int)(ent.x & 63u), (int)((ent.x >> 6) & 0x1FFFFu),
                          (int)(ent.x >> 23), __uint_as_float(ent.y), H2, out);
      }
    }
  }
}

// ---- accum6: row sort + unroll-8 register gather; FIRST skips out-read (R13/R14-validated core) ----
template<bool FIRST, bool LAST>
__global__ __launch_bounds__(256) void accum6_kernel(const uint2* __restrict__ gbuf,
                                                     int* __restrict__ cursor,
                                                     const uint16_t* __restrict__ H2,
                                                     float* __restrict__ out){
  __shared__ uint2 srt[BCAP];     // 20,480 B
  __shared__ int   cnt[BROWS];
  __shared__ int   pos[BROWS];
  __shared__ int   cur[BROWS];
  __shared__ int   entS;
  const int b = blockIdx.x;
  const int row0 = b * BROWS;
  const int tid = threadIdx.x;

  if (tid == 0){
    int e = cursor[b * CPAD]; if (e > BCAP) e = BCAP;
    entS = e;
  }
  if (tid < BROWS) cnt[tid] = 0;
  __syncthreads();
  const int entries = entS;
  if (tid == 0) cursor[b * CPAD] = 0;          // re-zero for next group (entS latched)
  const uint2* bbase = gbuf + (size_t)b * BCAP;

  // histogram over 64 row-keys (gbuf read 1)
  for (int i = tid; i < entries; i += 256)
    atomicAdd(&cnt[bbase[i].x & 63u], 1);
  __syncthreads();

  // exclusive prefix over 64 counts: wave 0, 1 count/lane
  if (tid < 64){
    int a = cnt[tid];
    int s = a;
#pragma unroll
    for (int d = 1; d < 64; d <<= 1){
      int t = __shfl_up(s, d);
      if (tid >= d) s += t;
    }
    int excl = s - a;
    pos[tid] = excl;
    cur[tid] = excl;
  }
  __syncthreads();

  // reorder into row-sorted LDS (gbuf read 2, L2-hot)
  for (int i = tid; i < entries; i += 256){
    uint2 e = bbase[i];
    int p = atomicAdd(&cur[e.x & 63u], 1);
    srt[p] = e;
  }
  __syncthreads();

  // process: 4 waves x 16 rows; register float2 accumulation; one store/RMW of out per row
  const int wave = tid >> 6, lane = tid & 63;
#pragma unroll
  for (int rr = 0; rr < 16; ++rr){
    int rl = wave * 16 + rr;
    int row = row0 + rl;
    if (row >= NN) break;
    int n  = cnt[rl];
    int b0 = pos[rl];
    float2 acc;
    if (FIRST){ acc.x = 0.f; acc.y = 0.f; }
    else acc = *(const float2*)(out + (size_t)row * OO + lane * 2);
    int k = 0;
    for (; k + 8 <= n; k += 8){
      float accx = 0.f, accy = 0.f;
#pragma unroll
      for (int j = 0; j < 8; ++j){
        uint2 e = srt[b0 + k + j];
        const uint16_t* h = H2 + (size_t)(e.x >> 23) * (NN * OO)
                               + (size_t)((e.x >> 6) & 0x1FFFFu) * OO;
        uint32_t q = ((const uint32_t*)h)[lane];
        float v = __uint_as_float(e.y);
        accx += v * bf2f((uint16_t)(q & 0xFFFFu));
        accy += v * bf2f((uint16_t)(q >> 16));
      }
      acc.x += accx; acc.y += accy;
    }
    for (; k < n; ++k){
      uint2 e = srt[b0 + k];
      const uint16_t* h = H2 + (size_t)(e.x >> 23) * (NN * OO)
                             + (size_t)((e.x >> 6) & 0x1FFFFu) * OO;
      uint32_t q = ((const uint32_t*)h)[lane];
      float v = __uint_as_float(e.y);
      acc.x += v * bf2f((uint16_t)(q & 0xFFFFu));
      acc.y += v * bf2f((uint16_t)(q >> 16));
    }
    if (LAST){ acc.x = fmaxf(acc.x, 0.f); acc.y = fmaxf(acc.y, 0.f); }
    *(float2*)(out + (size_t)row * OO + lane * 2) = acc;
  }
}

// ======== fallback (R0/R2-validated path pieces, only if ws too small) ========
__global__ void cast_bf16_kernel(const float* __restrict__ in, uint16_t* __restrict__ out, int n4){
  int i = blockIdx.x * blockDim.x + threadIdx.x;
  if (i < n4){
    float4 v = ((const float4*)in)[i];
    ushort4 o;
    o.x = f2bf(v.x); o.y = f2bf(v.y); o.z = f2bf(v.z); o.w = f2bf(v.w);
    ((ushort4*)out)[i] = o;
  }
}

__global__ __launch_bounds__(256) void gemm_kernel(const uint16_t* __restrict__ X16,
                                                   const uint16_t* __restrict__ VtS,
                                                   uint16_t* __restrict__ H16){
  const int wave = threadIdx.x >> 6;
  const int lane = threadIdx.x & 63;
  const int lr = lane & 15, lk = lane >> 4;
  const int row0 = blockIdx.x * 64 + wave * 16;
  f32x4 acc[8];
#pragma unroll
  for (int t = 0; t < 8; ++t) acc[t] = (f32x4){0.f, 0.f, 0.f, 0.f};
  int arow = row0 + lr; if (arow >= NN) arow = NN - 1;
  const uint16_t* aptr = X16 + (size_t)arow * DD + lk * 8;
#pragma unroll
  for (int kb = 0; kb < DD; kb += 32){
    short8 a = *(const short8*)(aptr + kb);
#pragma unroll
    for (int t = 0; t < 8; ++t){
      short8 b = *(const short8*)(VtS + (size_t)(t * 16 + lr) * DD + kb + lk * 8);
      acc[t] = __builtin_amdgcn_mfma_f32_16x16x32_bf16(a, b, acc[t], 0, 0, 0);
    }
  }
#pragma unroll
  for (int t = 0; t < 8; ++t){
#pragma unroll
    for (int j = 0; j < 4; ++j){
      int r = row0 + lk * 4 + j;
      if (r < NN) H16[(size_t)r * OO + t * 16 + lr] = f2bf(acc[t][j]);
    }
  }
}

__global__ __launch_bounds__(256) void spmm_kernel(const int* __restrict__ rows,
                                                   const int* __restrict__ cols,
                                                   const float* __restrict__ vals,
                                                   const uint16_t* __restrict__ H16,
                                                   float* __restrict__ out, int E){
  const int lane = threadIdx.x & 63;
  const int gwave = (int)((blockIdx.x * blockDim.x + threadIdx.x) >> 6);
  const int nw = (gridDim.x * blockDim.x) >> 6;
  for (int base = gwave * 64; base < E; base += nw * 64){
    int cnt = E - base; if (cnt > 64) cnt = 64;
    int r = 0, c = 0; float v = 0.f;
    if (lane < cnt){
      r = rows[base + lane]; c = cols[base + lane]; v = vals[base + lane];
    }
    for (int k = 0; k < cnt; ++k){
      int rr = __shfl(r, k);
      int cc = __shfl(c, k);
      float vv = __shfl(v, k);
      uint32_t pair = *(const uint32_t*)(H16 + (size_t)cc * OO + lane * 2);
      float* dst = out + (size_t)rr * OO + lane * 2;
      unsafeAtomicAdd(dst,     vv * bf2f((uint16_t)(pair & 0xFFFFu)));
      unsafeAtomicAdd(dst + 1, vv * bf2f((uint16_t)(pair >> 16)));
    }
  }
}

__global__ void relu_kernel(float* __restrict__ out, int n4){
  int i = blockIdx.x * blockDim.x + threadIdx.x;
  if (i < n4){
    float4 v = ((float4*)out)[i];
    v.x = fmaxf(v.x, 0.f); v.y = fmaxf(v.y, 0.f);
    v.z = fmaxf(v.z, 0.f); v.w = fmaxf(v.w, 0.f);
    ((float4*)out)[i] = v;
  }
}
// =============================================================================

extern "C" void kernel_launch(void* const* d_in, const int* in_sizes, int n_in,
                              void* d_out, int out_size, void* d_ws, size_t ws_size,
                              hipStream_t stream){
  const float* features = (const float*)d_in[0];
  const int*   rows     = (const int*)d_in[1];
  const int*   cols     = (const int*)d_in[2];
  const float* vals     = (const float*)d_in[3];
  const float* W        = (const float*)d_in[4];
  const float* Wc       = (const float*)d_in[5];
  float* out = (float*)d_out;
  const int E = in_sizes[1] / NS;

  char* ws = (char*)d_ws;
  // ---- main layout ----
  uint16_t* Vt     = (uint16_t*)ws;                     //    262,144
  uint16_t* H2     = (uint16_t*)(ws + 262144);          // 51,200,000 (2 relations)
  int*      cursor = (int*)     (ws + 51462144);        //    100,032 (1563 x 64B padded)
  uint2*    gbuf   = (uint2*)   (ws + 51562176);        // 32,010,240 (1563 x 2560 x 8B)
  const size_t NEEDED = 51562176 + (size_t)NBUCK * BCAP * 8;   // 83,572,416 < proven ws >= 90,262,144

  if (ws_size >= NEEDED){
    vt_kernel<<<NS * OO, DD, 0, stream>>>(W, Wc, Vt);
    hipMemsetAsync(cursor, 0, (size_t)NBUCK * CPAD * sizeof(int), stream);  // once; accum re-zeroes
    const int chunk  = (2 * E + 255) / 256;
    const int rounds = (chunk + EPT * 1024 - 1) / (EPT * 1024);
    for (int g = 0; g < 4; ++g){
      gemm2_kernel<<<(NN + 63) / 64, 256, 0, stream>>>(
          features, Vt + (size_t)(2 * g) * OO * DD, H2);
      bin6_kernel<<<256, 1024, 0, stream>>>(
          rows + (size_t)(2 * g) * E, cols + (size_t)(2 * g) * E, vals + (size_t)(2 * g) * E,
          H2, cursor, gbuf, out, E, chunk, rounds);
      if (g == 0)
        accum6_kernel<true, false><<<NBUCK, 256, 0, stream>>>(gbuf, cursor, H2, out);
      else if (g == 3)
        accum6_kernel<false, true><<<NBUCK, 256, 0, stream>>>(gbuf, cursor, H2, out);
      else
        accum6_kernel<false, false><<<NBUCK, 256, 0, stream>>>(gbuf, cursor, H2, out);
    }
    return;
  }

  // ---- fallback: cast + per-relation gemm + atomic spmm (R0/R2-validated) ----
  uint16_t* X16 = (uint16_t*)ws;                        // 25,600,000
  uint16_t* VtF = (uint16_t*)(ws + 25600000);           //    262,144
  uint16_t* H16 = (uint16_t*)(ws + 25862144);           // 25,600,000
  hipMemsetAsync(d_out, 0, (size_t)out_size * sizeof(float), stream);
  cast_bf16_kernel<<<(NN * DD / 4 + 255) / 256, 256, 0, stream>>>(features, X16, NN * DD / 4);
  vt_kernel<<<NS * OO, DD, 0, stream>>>(W, Wc, VtF);
  for (int s = 0; s < NS; ++s){
    gemm_kernel<<<(NN + 63) / 64, 256, 0, stream>>>(X16, VtF + (size_t)s * DD * OO, H16);
    spmm_kernel<<<4096, 256, 0, stream>>>(rows + (size_t)s * E, cols + (size_t)s * E,
                                          vals + (size_t)s * E, H16, out, E);
  }
  relu_kernel<<<(NN * OO / 4 + 255) / 256, 256, 0, stream>>>(out, NN * OO / 4);
}

// Round 16
// 959.572 us; speedup vs baseline: 1.1344x; 1.0095x over previous
//
#include <hip/hip_runtime.h>
#include <hip/hip_bf16.h>
#include <stdint.h>

#define NN 100000   // nodes
#define DD 128      // input dim
#define OO 128      // output dim
#define NS 8        // relations
#define NB 4        // bases

#define BROWS 64    // rows per bucket
#define NBUCK 1563  // ceil(NN/BROWS)
#define SDEPTH 12   // bin LDS staging depth per bucket
#define BCAP 2560   // per-bucket capacity, 2-relation group (mean 2048 + 11 sigma)
#define CPAD 16     // cursor padding (ints) = 64B per counter
#define EPT 8       // bin: edges per thread per round
#define EPTA 10     // accum: register entries per thread (10*256 = 2560 = BCAP)

typedef __attribute__((ext_vector_type(8))) short short8;
typedef __attribute__((ext_vector_type(4))) float f32x4;

__device__ __forceinline__ float bf2f(uint16_t u){
  union { uint32_t i; float f; } x; x.i = ((uint32_t)u) << 16; return x.f;
}
__device__ __forceinline__ uint16_t f2bf(float f){
  union { float f; uint32_t i; } x; x.f = f;
  uint32_t r = (x.i + 0x7FFFu + ((x.i >> 16) & 1u)) >> 16;  // RNE
  return (uint16_t)r;
}

// ---- effective per-relation weight, TRANSPOSED: Vt[s][o][d] = M_s[d][o] ----
// M_s[d,o] = sum_b W_comp[d&7, b] * W[b*128 + s*16 + (d>>3), o]  (validated R1-R15)
__global__ void vt_kernel(const float* __restrict__ W, const float* __restrict__ Wc,
                          uint16_t* __restrict__ Vt){
  int d  = threadIdx.x;
  int so = blockIdx.x;
  int s = so >> 7, o = so & 127;
  int wrow = s * 16 + (d >> 3);
  int wci  = (d & 7) * NB;
  float acc = 0.f;
#pragma unroll
  for (int b = 0; b < NB; ++b)
    acc += Wc[wci + b] * W[(b * DD + wrow) * OO + o];
  Vt[so * DD + d] = f2bf(acc);
}

// ---- gemm2: H_{s0}, H_{s0+1} = X @ M; reads f32 X once, casts in-register (R10-validated) ----
__global__ __launch_bounds__(256) void gemm2_kernel(const float* __restrict__ X,
                                                    const uint16_t* __restrict__ Vt2,
                                                    uint16_t* __restrict__ H2){
  const int wave = threadIdx.x >> 6;
  const int lane = threadIdx.x & 63;
  const int lr = lane & 15, lk = lane >> 4;
  const int row0 = blockIdx.x * 64 + wave * 16;

  int arow = row0 + lr; if (arow >= NN) arow = NN - 1;
  const float* ap = X + (size_t)arow * DD;
  short8 a[4];
#pragma unroll
  for (int kb = 0; kb < 4; ++kb){
    float4 f0 = *(const float4*)(ap + kb * 32 + lk * 8);
    float4 f1 = *(const float4*)(ap + kb * 32 + lk * 8 + 4);
    short8 t;
    t[0] = (short)f2bf(f0.x); t[1] = (short)f2bf(f0.y);
    t[2] = (short)f2bf(f0.z); t[3] = (short)f2bf(f0.w);
    t[4] = (short)f2bf(f1.x); t[5] = (short)f2bf(f1.y);
    t[6] = (short)f2bf(f1.z); t[7] = (short)f2bf(f1.w);
    a[kb] = t;
  }

  for (int j = 0; j < 2; ++j){
    f32x4 acc[8];
#pragma unroll
    for (int t = 0; t < 8; ++t) acc[t] = (f32x4){0.f, 0.f, 0.f, 0.f};
    const uint16_t* vb = Vt2 + (size_t)j * OO * DD;
#pragma unroll
    for (int kb = 0; kb < 4; ++kb){
#pragma unroll
      for (int t = 0; t < 8; ++t){
        short8 b = *(const short8*)(vb + (size_t)(t * 16 + lr) * DD + kb * 32 + lk * 8);
        acc[t] = __builtin_amdgcn_mfma_f32_16x16x32_bf16(a[kb], b, acc[t], 0, 0, 0);
      }
    }
    uint16_t* hs = H2 + (size_t)j * NN * OO;
#pragma unroll
    for (int t = 0; t < 8; ++t){
#pragma unroll
      for (int jj = 0; jj < 4; ++jj){
        int r = row0 + lk * 4 + jj;
        if (r < NN) hs[(size_t)r * OO + t * 16 + lr] = f2bf(acc[t][jj]);
      }
    }
  }
}

// entry encode: rowlocal[0:5], col[6:22], srel[23]
__device__ __noinline__ void overflow_add(int r, int c, int srel, float v,
                                          const uint16_t* __restrict__ H2,
                                          float* __restrict__ out){
  const uint16_t* h = H2 + (size_t)srel * NN * OO + (size_t)c * OO;
  float* dst = out + (size_t)r * OO;
  for (int d = 0; d < OO; ++d) unsafeAtomicAdd(dst + d, v * bf2f(h[d]));
}

// ---- bin6: multisplit, 8 edges/thread/round (2 rounds, 4 barriers), SDEPTH 12 (R15-validated) ----
__global__ __launch_bounds__(1024) void bin6_kernel(const int* __restrict__ rows2,
                                                    const int* __restrict__ cols2,
                                                    const float* __restrict__ vals2,
                                                    const uint16_t* __restrict__ H2,
                                                    int* __restrict__ cursor,
                                                    uint2* __restrict__ gbuf,
                                                    float* __restrict__ out,
                                                    int E, int chunk, int rounds){
  __shared__ uint2 stage[NBUCK][SDEPTH];   // 150,048 B
  __shared__ int   scnt[NBUCK];            //   6,252 B
  const int tid = threadIdx.x;
  const int E2 = 2 * E;
  for (int i = tid; i < NBUCK; i += 1024) scnt[i] = 0;
  __syncthreads();
  const int e0 = blockIdx.x * chunk;
  for (int rd = 0; rd < rounds; ++rd){
    int r2[EPT], c2[EPT]; float v2[EPT]; uint32_t sr2[EPT]; bool ok[EPT];
#pragma unroll
    for (int k = 0; k < EPT; ++k){
      int idx = (rd * EPT + k) * 1024 + tid;
      int e = e0 + idx;
      ok[k] = (idx < chunk && e < E2);
      if (ok[k]){
        r2[k] = rows2[e]; c2[k] = cols2[e]; v2[k] = vals2[e];
        sr2[k] = (e >= E) ? 1u : 0u;
      }
    }
#pragma unroll
    for (int k = 0; k < EPT; ++k){
      if (ok[k]){
        int b = r2[k] >> 6;
        uint2 ent = make_uint2((uint32_t)(r2[k] & 63) | ((uint32_t)c2[k] << 6) | (sr2[k] << 23),
                               __float_as_uint(v2[k]));
        int sp = atomicAdd(&scnt[b], 1);
        if (sp < SDEPTH){
          stage[b][sp] = ent;
        } else {                               // rare spill: direct to gbuf
          int pos = atomicAdd(&cursor[b * CPAD], 1);
          if (pos < BCAP) gbuf[(size_t)b * BCAP + pos] = ent;
          else overflow_add(r2[k], c2[k], (int)sr2[k], v2[k], H2, out);
        }
      }
    }
    __syncthreads();
    for (int b = tid; b < NBUCK; b += 1024){
      if (scnt[b] >= SDEPTH){
        int pos = atomicAdd(&cursor[b * CPAD], SDEPTH);
#pragma unroll
        for (int i = 0; i < SDEPTH; ++i){
          uint2 ent = stage[b][i];
          if (pos + i < BCAP) gbuf[(size_t)b * BCAP + pos + i] = ent;
          else overflow_add((b << 6) | (int)(ent.x & 63u), (int)((ent.x >> 6) & 0x1FFFFu),
                            (int)(ent.x >> 23), __uint_as_float(ent.y), H2, out);
        }
        scnt[b] = 0;
      }
    }
    __syncthreads();
  }
  for (int b = tid; b < NBUCK; b += 1024){
    int n = scnt[b]; if (n > SDEPTH) n = SDEPTH;
    if (n > 0){
      int pos = atomicAdd(&cursor[b * CPAD], n);
      for (int i = 0; i < n; ++i){
        uint2 ent = stage[b][i];
        if (pos + i < BCAP) gbuf[(size_t)b * BCAP + pos + i] = ent;
        else overflow_add((b << 6) | (int)(ent.x & 63u), (int)((ent.x >> 6) & 0x1FFFFu),
                          (int)(ent.x >> 23), __uint_as_float(ent.y), H2, out);
      }
    }
  }
}

// ---- accum7: single gbuf read into registers; histogram+reorder from regs; unroll-8 gather ----
template<bool FIRST, bool LAST>
__global__ __launch_bounds__(256) void accum7_kernel(const uint2* __restrict__ gbuf,
                                                     int* __restrict__ cursor,
                                                     const uint16_t* __restrict__ H2,
                                                     float* __restrict__ out){
  __shared__ uint2 srt[BCAP];     // 20,480 B
  __shared__ int   cnt[BROWS];
  __shared__ int   pos[BROWS];
  __shared__ int   cur[BROWS];
  __shared__ int   entS;
  const int b = blockIdx.x;
  const int row0 = b * BROWS;
  const int tid = threadIdx.x;

  if (tid == 0){
    int e = cursor[b * CPAD]; if (e > BCAP) e = BCAP;
    entS = e;
  }
  if (tid < BROWS) cnt[tid] = 0;
  __syncthreads();
  const int entries = entS;
  if (tid == 0) cursor[b * CPAD] = 0;          // re-zero for next group (entS latched)
  const uint2* bbase = gbuf + (size_t)b * BCAP;

  // single gbuf read -> registers (static indices, stays in VGPRs)
  uint2 ereg[EPTA];
#pragma unroll
  for (int k = 0; k < EPTA; ++k){
    int i = tid + k * 256;
    ereg[k] = (i < entries) ? bbase[i] : make_uint2(0u, 0u);
  }
  // histogram over 64 row-keys from registers
#pragma unroll
  for (int k = 0; k < EPTA; ++k){
    int i = tid + k * 256;
    if (i < entries) atomicAdd(&cnt[ereg[k].x & 63u], 1);
  }
  __syncthreads();

  // exclusive prefix over 64 counts: wave 0, 1 count/lane
  if (tid < 64){
    int a = cnt[tid];
    int s = a;
#pragma unroll
    for (int d = 1; d < 64; d <<= 1){
      int t = __shfl_up(s, d);
      if (tid >= d) s += t;
    }
    int excl = s - a;
    pos[tid] = excl;
    cur[tid] = excl;
  }
  __syncthreads();

  // reorder from registers into row-sorted LDS
#pragma unroll
  for (int k = 0; k < EPTA; ++k){
    int i = tid + k * 256;
    if (i < entries){
      int p = atomicAdd(&cur[ereg[k].x & 63u], 1);
      srt[p] = ereg[k];
    }
  }
  __syncthreads();

  // process: 4 waves x 16 rows; register float2 accumulation; one store/RMW of out per row
  const int wave = tid >> 6, lane = tid & 63;
#pragma unroll
  for (int rr = 0; rr < 16; ++rr){
    int rl = wave * 16 + rr;
    int row = row0 + rl;
    if (row >= NN) break;
    int n  = cnt[rl];
    int b0 = pos[rl];
    float2 acc;
    if (FIRST){ acc.x = 0.f; acc.y = 0.f; }
    else acc = *(const float2*)(out + (size_t)row * OO + lane * 2);
    int k = 0;
    for (; k + 8 <= n; k += 8){
      float accx = 0.f, accy = 0.f;
#pragma unroll
      for (int j = 0; j < 8; ++j){
        uint2 e = srt[b0 + k + j];
        const uint16_t* h = H2 + (size_t)(e.x >> 23) * (NN * OO)
                               + (size_t)((e.x >> 6) & 0x1FFFFu) * OO;
        uint32_t q = ((const uint32_t*)h)[lane];
        float v = __uint_as_float(e.y);
        accx += v * bf2f((uint16_t)(q & 0xFFFFu));
        accy += v * bf2f((uint16_t)(q >> 16));
      }
      acc.x += accx; acc.y += accy;
    }
    for (; k < n; ++k){
      uint2 e = srt[b0 + k];
      const uint16_t* h = H2 + (size_t)(e.x >> 23) * (NN * OO)
                             + (size_t)((e.x >> 6) & 0x1FFFFu) * OO;
      uint32_t q = ((const uint32_t*)h)[lane];
      float v = __uint_as_float(e.y);
      acc.x += v * bf2f((uint16_t)(q & 0xFFFFu));
      acc.y += v * bf2f((uint16_t)(q >> 16));
    }
    if (LAST){ acc.x = fmaxf(acc.x, 0.f); acc.y = fmaxf(acc.y, 0.f); }
    *(float2*)(out + (size_t)row * OO + lane * 2) = acc;
  }
}

// ======== fallback (R0/R2-validated path pieces, only if ws too small) ========
__global__ void cast_bf16_kernel(const float* __restrict__ in, uint16_t* __restrict__ out, int n4){
  int i = blockIdx.x * blockDim.x + threadIdx.x;
  if (i < n4){
    float4 v = ((const float4*)in)[i];
    ushort4 o;
    o.x = f2bf(v.x); o.y = f2bf(v.y); o.z = f2bf(v.z); o.w = f2bf(v.w);
    ((ushort4*)out)[i] = o;
  }
}

__global__ __launch_bounds__(256) void gemm_kernel(const uint16_t* __restrict__ X16,
                                                   const uint16_t* __restrict__ VtS,
                                                   uint16_t* __restrict__ H16){
  const int wave = threadIdx.x >> 6;
  const int lane = threadIdx.x & 63;
  const int lr = lane & 15, lk = lane >> 4;
  const int row0 = blockIdx.x * 64 + wave * 16;
  f32x4 acc[8];
#pragma unroll
  for (int t = 0; t < 8; ++t) acc[t] = (f32x4){0.f, 0.f, 0.f, 0.f};
  int arow = row0 + lr; if (arow >= NN) arow = NN - 1;
  const uint16_t* aptr = X16 + (size_t)arow * DD + lk * 8;
#pragma unroll
  for (int kb = 0; kb < DD; kb += 32){
    short8 a = *(const short8*)(aptr + kb);
#pragma unroll
    for (int t = 0; t < 8; ++t){
      short8 b = *(const short8*)(VtS + (size_t)(t * 16 + lr) * DD + kb + lk * 8);
      acc[t] = __builtin_amdgcn_mfma_f32_16x16x32_bf16(a, b, acc[t], 0, 0, 0);
    }
  }
#pragma unroll
  for (int t = 0; t < 8; ++t){
#pragma unroll
    for (int j = 0; j < 4; ++j){
      int r = row0 + lk * 4 + j;
      if (r < NN) H16[(size_t)r * OO + t * 16 + lr] = f2bf(acc[t][j]);
    }
  }
}

__global__ __launch_bounds__(256) void spmm_kernel(const int* __restrict__ rows,
                                                   const int* __restrict__ cols,
                                                   const float* __restrict__ vals,
                                                   const uint16_t* __restrict__ H16,
                                                   float* __restrict__ out, int E){
  const int lane = threadIdx.x & 63;
  const int gwave = (int)((blockIdx.x * blockDim.x + threadIdx.x) >> 6);
  const int nw = (gridDim.x * blockDim.x) >> 6;
  for (int base = gwave * 64; base < E; base += nw * 64){
    int cnt = E - base; if (cnt > 64) cnt = 64;
    int r = 0, c = 0; float v = 0.f;
    if (lane < cnt){
      r = rows[base + lane]; c = cols[base + lane]; v = vals[base + lane];
    }
    for (int k = 0; k < cnt; ++k){
      int rr = __shfl(r, k);
      int cc = __shfl(c, k);
      float vv = __shfl(v, k);
      uint32_t pair = *(const uint32_t*)(H16 + (size_t)cc * OO + lane * 2);
      float* dst = out + (size_t)rr * OO + lane * 2;
      unsafeAtomicAdd(dst,     vv * bf2f((uint16_t)(pair & 0xFFFFu)));
      unsafeAtomicAdd(dst + 1, vv * bf2f((uint16_t)(pair >> 16)));
    }
  }
}

__global__ void relu_kernel(float* __restrict__ out, int n4){
  int i = blockIdx.x * blockDim.x + threadIdx.x;
  if (i < n4){
    float4 v = ((float4*)out)[i];
    v.x = fmaxf(v.x, 0.f); v.y = fmaxf(v.y, 0.f);
    v.z = fmaxf(v.z, 0.f); v.w = fmaxf(v.w, 0.f);
    ((float4*)out)[i] = v;
  }
}
// =============================================================================

extern "C" void kernel_launch(void* const* d_in, const int* in_sizes, int n_in,
                              void* d_out, int out_size, void* d_ws, size_t ws_size,
                              hipStream_t stream){
  const float* features = (const float*)d_in[0];
  const int*   rows     = (const int*)d_in[1];
  const int*   cols     = (const int*)d_in[2];
  const float* vals     = (const float*)d_in[3];
  const float* W        = (const float*)d_in[4];
  const float* Wc       = (const float*)d_in[5];
  float* out = (float*)d_out;
  const int E = in_sizes[1] / NS;

  char* ws = (char*)d_ws;
  // ---- main layout ----
  uint16_t* Vt     = (uint16_t*)ws;                     //    262,144
  uint16_t* H2     = (uint16_t*)(ws + 262144);          // 51,200,000 (2 relations)
  int*      cursor = (int*)     (ws + 51462144);        //    100,032 (1563 x 64B padded)
  uint2*    gbuf   = (uint2*)   (ws + 51562176);        // 32,010,240 (1563 x 2560 x 8B)
  const size_t NEEDED = 51562176 + (size_t)NBUCK * BCAP * 8;   // 83,572,416 < proven ws >= 90,262,144

  if (ws_size >= NEEDED){
    vt_kernel<<<NS * OO, DD, 0, stream>>>(W, Wc, Vt);
    hipMemsetAsync(cursor, 0, (size_t)NBUCK * CPAD * sizeof(int), stream);  // once; accum re-zeroes
    const int chunk  = (2 * E + 255) / 256;
    const int rounds = (chunk + EPT * 1024 - 1) / (EPT * 1024);
    for (int g = 0; g < 4; ++g){
      gemm2_kernel<<<(NN + 63) / 64, 256, 0, stream>>>(
          features, Vt + (size_t)(2 * g) * OO * DD, H2);
      bin6_kernel<<<256, 1024, 0, stream>>>(
          rows + (size_t)(2 * g) * E, cols + (size_t)(2 * g) * E, vals + (size_t)(2 * g) * E,
          H2, cursor, gbuf, out, E, chunk, rounds);
      if (g == 0)
        accum7_kernel<true, false><<<NBUCK, 256, 0, stream>>>(gbuf, cursor, H2, out);
      else if (g == 3)
        accum7_kernel<false, true><<<NBUCK, 256, 0, stream>>>(gbuf, cursor, H2, out);
      else
        accum7_kernel<false, false><<<NBUCK, 256, 0, stream>>>(gbuf, cursor, H2, out);
    }
    return;
  }

  // ---- fallback: cast + per-relation gemm + atomic spmm (R0/R2-validated) ----
  uint16_t* X16 = (uint16_t*)ws;                        // 25,600,000
  uint16_t* VtF = (uint16_t*)(ws + 25600000);           //    262,144
  uint16_t* H16 = (uint16_t*)(ws + 25862144);           // 25,600,000
  hipMemsetAsync(d_out, 0, (size_t)out_size * sizeof(float), stream);
  cast_bf16_kernel<<<(NN * DD / 4 + 255) / 256, 256, 0, stream>>>(features, X16, NN * DD / 4);
  vt_kernel<<<NS * OO, DD, 0, stream>>>(W, Wc, VtF);
  for (int s = 0; s < NS; ++s){
    gemm_kernel<<<(NN + 63) / 64, 256, 0, stream>>>(X16, VtF + (size_t)s * DD * OO, H16);
    spmm_kernel<<<4096, 256, 0, stream>>>(rows + (size_t)s * E, cols + (size_t)s * E,
                                          vals + (size_t)s * E, H16, out, E);
  }
  relu_kernel<<<(NN * OO / 4 + 255) / 256, 256, 0, stream>>>(out, NN * OO / 4);
}

// Round 18
// 957.032 us; speedup vs baseline: 1.1374x; 1.0027x over previous
//
#include <hip/hip_runtime.h>
#include <hip/hip_bf16.h>
#include <stdint.h>

#define NN 100000   // nodes
#define DD 128      // input dim
#define OO 128      // output dim
#define NS 8        // relations
#define NB 4        // bases

#define BROWS 64    // rows per bucket
#define NBUCK 1563  // ceil(NN/BROWS)
#define SDEPTH 12   // bin LDS staging depth per bucket
#define BCAP 2560   // per-bucket capacity, 2-relation group (mean 2048 + 11 sigma)
#define CPAD 16     // cursor padding (ints) = 64B per counter
#define EPT 8       // bin: edges per thread per round
#define EPTA 10     // accum: register entries per thread (10*256 = 2560 = BCAP)

typedef __attribute__((ext_vector_type(8))) short short8;
typedef __attribute__((ext_vector_type(4))) float f32x4;

__device__ __forceinline__ float bf2f(uint16_t u){
  union { uint32_t i; float f; } x; x.i = ((uint32_t)u) << 16; return x.f;
}
__device__ __forceinline__ uint16_t f2bf(float f){
  union { float f; uint32_t i; } x; x.f = f;
  uint32_t r = (x.i + 0x7FFFu + ((x.i >> 16) & 1u)) >> 16;  // RNE
  return (uint16_t)r;
}

// ---- effective per-relation weight, TRANSPOSED: Vt[s][o][d] = M_s[d][o] ----
// M_s[d,o] = sum_b W_comp[d&7, b] * W[b*128 + s*16 + (d>>3), o]  (validated R1-R16)
__global__ void vt_kernel(const float* __restrict__ W, const float* __restrict__ Wc,
                          uint16_t* __restrict__ Vt){
  int d  = threadIdx.x;
  int so = blockIdx.x;
  int s = so >> 7, o = so & 127;
  int wrow = s * 16 + (d >> 3);
  int wci  = (d & 7) * NB;
  float acc = 0.f;
#pragma unroll
  for (int b = 0; b < NB; ++b)
    acc += Wc[wci + b] * W[(b * DD + wrow) * OO + o];
  Vt[so * DD + d] = f2bf(acc);
}

// ---- gemm2: H_{s0}, H_{s0+1} = X @ M; reads f32 X once, casts in-register (R10-validated) ----
__global__ __launch_bounds__(256) void gemm2_kernel(const float* __restrict__ X,
                                                    const uint16_t* __restrict__ Vt2,
                                                    uint16_t* __restrict__ H2){
  const int wave = threadIdx.x >> 6;
  const int lane = threadIdx.x & 63;
  const int lr = lane & 15, lk = lane >> 4;
  const int row0 = blockIdx.x * 64 + wave * 16;

  int arow = row0 + lr; if (arow >= NN) arow = NN - 1;
  const float* ap = X + (size_t)arow * DD;
  short8 a[4];
#pragma unroll
  for (int kb = 0; kb < 4; ++kb){
    float4 f0 = *(const float4*)(ap + kb * 32 + lk * 8);
    float4 f1 = *(const float4*)(ap + kb * 32 + lk * 8 + 4);
    short8 t;
    t[0] = (short)f2bf(f0.x); t[1] = (short)f2bf(f0.y);
    t[2] = (short)f2bf(f0.z); t[3] = (short)f2bf(f0.w);
    t[4] = (short)f2bf(f1.x); t[5] = (short)f2bf(f1.y);
    t[6] = (short)f2bf(f1.z); t[7] = (short)f2bf(f1.w);
    a[kb] = t;
  }

  for (int j = 0; j < 2; ++j){
    f32x4 acc[8];
#pragma unroll
    for (int t = 0; t < 8; ++t) acc[t] = (f32x4){0.f, 0.f, 0.f, 0.f};
    const uint16_t* vb = Vt2 + (size_t)j * OO * DD;
#pragma unroll
    for (int kb = 0; kb < 4; ++kb){
#pragma unroll
      for (int t = 0; t < 8; ++t){
        short8 b = *(const short8*)(vb + (size_t)(t * 16 + lr) * DD + kb * 32 + lk * 8);
        acc[t] = __builtin_amdgcn_mfma_f32_16x16x32_bf16(a[kb], b, acc[t], 0, 0, 0);
      }
    }
    uint16_t* hs = H2 + (size_t)j * NN * OO;
#pragma unroll
    for (int t = 0; t < 8; ++t){
#pragma unroll
      for (int jj = 0; jj < 4; ++jj){
        int r = row0 + lk * 4 + jj;
        if (r < NN) hs[(size_t)r * OO + t * 16 + lr] = f2bf(acc[t][jj]);
      }
    }
  }
}

// entry encode: rowlocal[0:5], col[6:22], srel[23]
__device__ __noinline__ void overflow_add(int r, int c, int srel, float v,
                                          const uint16_t* __restrict__ H2,
                                          float* __restrict__ out){
  const uint16_t* h = H2 + (size_t)srel * NN * OO + (size_t)c * OO;
  float* dst = out + (size_t)r * OO;
  for (int d = 0; d < OO; ++d) unsafeAtomicAdd(dst + d, v * bf2f(h[d]));
}

// ---- bin6: multisplit, 8 edges/thread/round (2 rounds, 4 barriers), SDEPTH 12 (R15-validated) ----
__global__ __launch_bounds__(1024) void bin6_kernel(const int* __restrict__ rows2,
                                                    const int* __restrict__ cols2,
                                                    const float* __restrict__ vals2,
                                                    const uint16_t* __restrict__ H2,
                                                    int* __restrict__ cursor,
                                                    uint2* __restrict__ gbuf,
                                                    float* __restrict__ out,
                                                    int E, int chunk, int rounds){
  __shared__ uint2 stage[NBUCK][SDEPTH];   // 150,048 B
  __shared__ int   scnt[NBUCK];            //   6,252 B
  const int tid = threadIdx.x;
  const int E2 = 2 * E;
  for (int i = tid; i < NBUCK; i += 1024) scnt[i] = 0;
  __syncthreads();
  const int e0 = blockIdx.x * chunk;
  for (int rd = 0; rd < rounds; ++rd){
    int r2[EPT], c2[EPT]; float v2[EPT]; uint32_t sr2[EPT]; bool ok[EPT];
#pragma unroll
    for (int k = 0; k < EPT; ++k){
      int idx = (rd * EPT + k) * 1024 + tid;
      int e = e0 + idx;
      ok[k] = (idx < chunk && e < E2);
      if (ok[k]){
        r2[k] = rows2[e]; c2[k] = cols2[e]; v2[k] = vals2[e];
        sr2[k] = (e >= E) ? 1u : 0u;
      }
    }
#pragma unroll
    for (int k = 0; k < EPT; ++k){
      if (ok[k]){
        int b = r2[k] >> 6;
        uint2 ent = make_uint2((uint32_t)(r2[k] & 63) | ((uint32_t)c2[k] << 6) | (sr2[k] << 23),
                               __float_as_uint(v2[k]));
        int sp = atomicAdd(&scnt[b], 1);
        if (sp < SDEPTH){
          stage[b][sp] = ent;
        } else {                               // rare spill: direct to gbuf
          int pos = atomicAdd(&cursor[b * CPAD], 1);
          if (pos < BCAP) gbuf[(size_t)b * BCAP + pos] = ent;
          else overflow_add(r2[k], c2[k], (int)sr2[k], v2[k], H2, out);
        }
      }
    }
    __syncthreads();
    for (int b = tid; b < NBUCK; b += 1024){
      if (scnt[b] >= SDEPTH){
        int pos = atomicAdd(&cursor[b * CPAD], SDEPTH);
#pragma unroll
        for (int i = 0; i < SDEPTH; ++i){
          uint2 ent = stage[b][i];
          if (pos + i < BCAP) gbuf[(size_t)b * BCAP + pos + i] = ent;
          else overflow_add((b << 6) | (int)(ent.x & 63u), (int)((ent.x >> 6) & 0x1FFFFu),
                            (int)(ent.x >> 23), __uint_as_float(ent.y), H2, out);
        }
        scnt[b] = 0;
      }
    }
    __syncthreads();
  }
  for (int b = tid; b < NBUCK; b += 1024){
    int n = scnt[b]; if (n > SDEPTH) n = SDEPTH;
    if (n > 0){
      int pos = atomicAdd(&cursor[b * CPAD], n);
      for (int i = 0; i < n; ++i){
        uint2 ent = stage[b][i];
        if (pos + i < BCAP) gbuf[(size_t)b * BCAP + pos + i] = ent;
        else overflow_add((b << 6) | (int)(ent.x & 63u), (int)((ent.x >> 6) & 0x1FFFFu),
                          (int)(ent.x >> 23), __uint_as_float(ent.y), H2, out);
      }
    }
  }
}

// ---- accum7: single gbuf read into registers; histogram+reorder from regs; unroll-8 gather ----
template<bool FIRST, bool LAST>
__global__ __launch_bounds__(256) void accum7_kernel(const uint2* __restrict__ gbuf,
                                                     int* __restrict__ cursor,
                                                     const uint16_t* __restrict__ H2,
                                                     float* __restrict__ out){
  __shared__ uint2 srt[BCAP];     // 20,480 B
  __shared__ int   cnt[BROWS];
  __shared__ int   pos[BROWS];
  __shared__ int   cur[BROWS];
  __shared__ int   entS;
  const int b = blockIdx.x;
  const int row0 = b * BROWS;
  const int tid = threadIdx.x;

  if (tid == 0){
    int e = cursor[b * CPAD]; if (e > BCAP) e = BCAP;
    entS = e;
  }
  if (tid < BROWS) cnt[tid] = 0;
  __syncthreads();
  const int entries = entS;
  if (tid == 0) cursor[b * CPAD] = 0;          // re-zero for next group (entS latched)
  const uint2* bbase = gbuf + (size_t)b * BCAP;

  // single gbuf read -> registers (static indices, stays in VGPRs)
  uint2 ereg[EPTA];
#pragma unroll
  for (int k = 0; k < EPTA; ++k){
    int i = tid + k * 256;
    ereg[k] = (i < entries) ? bbase[i] : make_uint2(0u, 0u);
  }
  // histogram over 64 row-keys from registers
#pragma unroll
  for (int k = 0; k < EPTA; ++k){
    int i = tid + k * 256;
    if (i < entries) atomicAdd(&cnt[ereg[k].x & 63u], 1);
  }
  __syncthreads();

  // exclusive prefix over 64 counts: wave 0, 1 count/lane
  if (tid < 64){
    int a = cnt[tid];
    int s = a;
#pragma unroll
    for (int d = 1; d < 64; d <<= 1){
      int t = __shfl_up(s, d);
      if (tid >= d) s += t;
    }
    int excl = s - a;
    pos[tid] = excl;
    cur[tid] = excl;
  }
  __syncthreads();

  // reorder from registers into row-sorted LDS
#pragma unroll
  for (int k = 0; k < EPTA; ++k){
    int i = tid + k * 256;
    if (i < entries){
      int p = atomicAdd(&cur[ereg[k].x & 63u], 1);
      srt[p] = ereg[k];
    }
  }
  __syncthreads();

  // process: 4 waves x 16 rows; register float2 accumulation; one store/RMW of out per row
  const int wave = tid >> 6, lane = tid & 63;
#pragma unroll
  for (int rr = 0; rr < 16; ++rr){
    int rl = wave * 16 + rr;
    int row = row0 + rl;
    if (row >= NN) break;
    int n  = cnt[rl];
    int b0 = pos[rl];
    float2 acc;
    if (FIRST){ acc.x = 0.f; acc.y = 0.f; }
    else acc = *(const float2*)(out + (size_t)row * OO + lane * 2);
    int k = 0;
    for (; k + 8 <= n; k += 8){
      float accx = 0.f, accy = 0.f;
#pragma unroll
      for (int j = 0; j < 8; ++j){
        uint2 e = srt[b0 + k + j];
        const uint16_t* h = H2 + (size_t)(e.x >> 23) * (NN * OO)
                               + (size_t)((e.x >> 6) & 0x1FFFFu) * OO;
        uint32_t q = ((const uint32_t*)h)[lane];
        float v = __uint_as_float(e.y);
        accx += v * bf2f((uint16_t)(q & 0xFFFFu));
        accy += v * bf2f((uint16_t)(q >> 16));
      }
      acc.x += accx; acc.y += accy;
    }
    for (; k < n; ++k){
      uint2 e = srt[b0 + k];
      const uint16_t* h = H2 + (size_t)(e.x >> 23) * (NN * OO)
                             + (size_t)((e.x >> 6) & 0x1FFFFu) * OO;
      uint32_t q = ((const uint32_t*)h)[lane];
      float v = __uint_as_float(e.y);
      acc.x += v * bf2f((uint16_t)(q & 0xFFFFu));
      acc.y += v * bf2f((uint16_t)(q >> 16));
    }
    if (LAST){ acc.x = fmaxf(acc.x, 0.f); acc.y = fmaxf(acc.y, 0.f); }
    *(float2*)(out + (size_t)row * OO + lane * 2) = acc;
  }
}

// ======== fallback (R0/R2-validated path pieces, only if ws too small) ========
__global__ void cast_bf16_kernel(const float* __restrict__ in, uint16_t* __restrict__ out, int n4){
  int i = blockIdx.x * blockDim.x + threadIdx.x;
  if (i < n4){
    float4 v = ((const float4*)in)[i];
    ushort4 o;
    o.x = f2bf(v.x); o.y = f2bf(v.y); o.z = f2bf(v.z); o.w = f2bf(v.w);
    ((ushort4*)out)[i] = o;
  }
}

__global__ __launch_bounds__(256) void gemm_kernel(const uint16_t* __restrict__ X16,
                                                   const uint16_t* __restrict__ VtS,
                                                   uint16_t* __restrict__ H16){
  const int wave = threadIdx.x >> 6;
  const int lane = threadIdx.x & 63;
  const int lr = lane & 15, lk = lane >> 4;
  const int row0 = blockIdx.x * 64 + wave * 16;
  f32x4 acc[8];
#pragma unroll
  for (int t = 0; t < 8; ++t) acc[t] = (f32x4){0.f, 0.f, 0.f, 0.f};
  int arow = row0 + lr; if (arow >= NN) arow = NN - 1;
  const uint16_t* aptr = X16 + (size_t)arow * DD + lk * 8;
#pragma unroll
  for (int kb = 0; kb < DD; kb += 32){
    short8 a = *(const short8*)(aptr + kb);
#pragma unroll
    for (int t = 0; t < 8; ++t){
      short8 b = *(const short8*)(VtS + (size_t)(t * 16 + lr) * DD + kb + lk * 8);
      acc[t] = __builtin_amdgcn_mfma_f32_16x16x32_bf16(a, b, acc[t], 0, 0, 0);
    }
  }
#pragma unroll
  for (int t = 0; t < 8; ++t){
#pragma unroll
    for (int j = 0; j < 4; ++j){
      int r = row0 + lk * 4 + j;
      if (r < NN) H16[(size_t)r * OO + t * 16 + lr] = f2bf(acc[t][j]);
    }
  }
}

__global__ __launch_bounds__(256) void spmm_kernel(const int* __restrict__ rows,
                                                   const int* __restrict__ cols,
                                                   const float* __restrict__ vals,
                                                   const uint16_t* __restrict__ H16,
                                                   float* __restrict__ out, int E){
  const int lane = threadIdx.x & 63;
  const int gwave = (int)((blockIdx.x * blockDim.x + threadIdx.x) >> 6);
  const int nw = (gridDim.x * blockDim.x) >> 6;
  for (int base = gwave * 64; base < E; base += nw * 64){
    int cnt = E - base; if (cnt > 64) cnt = 64;
    int r = 0, c = 0; float v = 0.f;
    if (lane < cnt){
      r = rows[base + lane]; c = cols[base + lane]; v = vals[base + lane];
    }
    for (int k = 0; k < cnt; ++k){
      int rr = __shfl(r, k);
      int cc = __shfl(c, k);
      float vv = __shfl(v, k);
      uint32_t pair = *(const uint32_t*)(H16 + (size_t)cc * OO + lane * 2);
      float* dst = out + (size_t)rr * OO + lane * 2;
      unsafeAtomicAdd(dst,     vv * bf2f((uint16_t)(pair & 0xFFFFu)));
      unsafeAtomicAdd(dst + 1, vv * bf2f((uint16_t)(pair >> 16)));
    }
  }
}

__global__ void relu_kernel(float* __restrict__ out, int n4){
  int i = blockIdx.x * blockDim.x + threadIdx.x;
  if (i < n4){
    float4 v = ((float4*)out)[i];
    v.x = fmaxf(v.x, 0.f); v.y = fmaxf(v.y, 0.f);
    v.z = fmaxf(v.z, 0.f); v.w = fmaxf(v.w, 0.f);
    ((float4*)out)[i] = v;
  }
}
// =============================================================================

extern "C" void kernel_launch(void* const* d_in, const int* in_sizes, int n_in,
                              void* d_out, int out_size, void* d_ws, size_t ws_size,
                              hipStream_t stream){
  const float* features = (const float*)d_in[0];
  const int*   rows     = (const int*)d_in[1];
  const int*   cols     = (const int*)d_in[2];
  const float* vals     = (const float*)d_in[3];
  const float* W        = (const float*)d_in[4];
  const float* Wc       = (const float*)d_in[5];
  float* out = (float*)d_out;
  const int E = in_sizes[1] / NS;

  char* ws = (char*)d_ws;
  // ---- main layout ----
  uint16_t* Vt     = (uint16_t*)ws;                     //    262,144
  uint16_t* H2     = (uint16_t*)(ws + 262144);          // 51,200,000 (2 relations)
  int*      cursor = (int*)     (ws + 51462144);        //    100,032 (1563 x 64B padded)
  uint2*    gbuf   = (uint2*)   (ws + 51562176);        // 32,010,240 (1563 x 2560 x 8B)
  const size_t NEEDED = 51562176 + (size_t)NBUCK * BCAP * 8;   // 83,572,416 < proven ws >= 90,262,144

  if (ws_size >= NEEDED){
    vt_kernel<<<NS * OO, DD, 0, stream>>>(W, Wc, Vt);
    hipMemsetAsync(cursor, 0, (size_t)NBUCK * CPAD * sizeof(int), stream);  // once; accum re-zeroes
    const int chunk  = (2 * E + 255) / 256;
    const int rounds = (chunk + EPT * 1024 - 1) / (EPT * 1024);
    for (int g = 0; g < 4; ++g){
      gemm2_kernel<<<(NN + 63) / 64, 256, 0, stream>>>(
          features, Vt + (size_t)(2 * g) * OO * DD, H2);
      bin6_kernel<<<256, 1024, 0, stream>>>(
          rows + (size_t)(2 * g) * E, cols + (size_t)(2 * g) * E, vals + (size_t)(2 * g) * E,
          H2, cursor, gbuf, out, E, chunk, rounds);
      if (g == 0)
        accum7_kernel<true, false><<<NBUCK, 256, 0, stream>>>(gbuf, cursor, H2, out);
      else if (g == 3)
        accum7_kernel<false, true><<<NBUCK, 256, 0, stream>>>(gbuf, cursor, H2, out);
      else
        accum7_kernel<false, false><<<NBUCK, 256, 0, stream>>>(gbuf, cursor, H2, out);
    }
    return;
  }

  // ---- fallback: cast + per-relation gemm + atomic spmm (R0/R2-validated) ----
  uint16_t* X16 = (uint16_t*)ws;                        // 25,600,000
  uint16_t* VtF = (uint16_t*)(ws + 25600000);           //    262,144
  uint16_t* H16 = (uint16_t*)(ws + 25862144);           // 25,600,000
  hipMemsetAsync(d_out, 0, (size_t)out_size * sizeof(float), stream);
  cast_bf16_kernel<<<(NN * DD / 4 + 255) / 256, 256, 0, stream>>>(features, X16, NN * DD / 4);
  vt_kernel<<<NS * OO, DD, 0, stream>>>(W, Wc, VtF);
  for (int s = 0; s < NS; ++s){
    gemm_kernel<<<(NN + 63) / 64, 256, 0, stream>>>(X16, VtF + (size_t)s * DD * OO, H16);
    spmm_kernel<<<4096, 256, 0, stream>>>(rows + (size_t)s * E, cols + (size_t)s * E,
                                          vals + (size_t)s * E, H16, out, E);
  }
  relu_kernel<<<(NN * OO / 4 + 255) / 256, 256, 0, stream>>>(out, NN * OO / 4);
}